// Round 1
// baseline (867.201 us; speedup 1.0000x reference)
//
#include <hip/hip_runtime.h>
#include <cstdint>

// Transformer block, bf16 MFMA implementation.
// Pipeline: [w transposes->bf16] ln1 -> QKV gemm -> flash attn -> proj gemm(+res)
//           -> ln2 -> fc1 gemm(+bias,relu) -> fc2 gemm(+bias,+res) -> out (f32)

#define CDIM 1024
#define TSEQ 2048
#define NBATCH 4
#define NHEAD 16
#define HDIM 64
#define FDIM 4096

typedef unsigned short u16;
typedef __attribute__((ext_vector_type(8))) short s16x8;   // 8 bf16 in 4 VGPRs
typedef __attribute__((ext_vector_type(4))) float f32x4;

__device__ __forceinline__ u16 f2bu(float f) {             // f32 -> bf16 bits, RNE
    uint32_t u = __builtin_bit_cast(uint32_t, f);
    uint32_t r = (u + 0x7FFFu + ((u >> 16) & 1u)) >> 16;
    return (u16)r;
}

typedef __attribute__((address_space(3))) unsigned int lds_u32;
typedef __attribute__((address_space(1))) const unsigned int glb_u32;
__device__ __forceinline__ void gload_lds16(const void* g, void* l) {
    // async global->LDS, 16B per lane; LDS dest must be wave-uniform base
    __builtin_amdgcn_global_load_lds((glb_u32*)g, (lds_u32*)l, 16, 0, 0);
}

// ---------------- weight fp32 [K][N] -> bf16 transposed [N][K] ----------------
__global__ __launch_bounds__(256) void twb_k(const float* __restrict__ in,
                                             u16* __restrict__ out, int K, int N) {
    __shared__ float tile[32][33];
    int n0 = blockIdx.x * 32, k0 = blockIdx.y * 32;
    int tx = threadIdx.x & 31, ty = threadIdx.x >> 5;  // ty 0..7
#pragma unroll
    for (int i = 0; i < 32; i += 8)
        tile[ty + i][tx] = in[(size_t)(k0 + ty + i) * N + n0 + tx];
    __syncthreads();
#pragma unroll
    for (int i = 0; i < 32; i += 8)
        out[(size_t)(n0 + ty + i) * K + k0 + tx] = f2bu(tile[tx][ty + i]);
}

// ---------------- layernorm (f32 in, bf16 out), one row per block ----------------
__global__ __launch_bounds__(256) void ln_k(const float* __restrict__ x,
                                            const float* __restrict__ w,
                                            u16* __restrict__ out) {
    int row = blockIdx.x;
    int t = threadIdx.x;
    const float4* xr = (const float4*)(x + (size_t)row * CDIM);
    float4 v = xr[t];
    float s = v.x + v.y + v.z + v.w;
    float sq = v.x * v.x + v.y * v.y + v.z * v.z + v.w * v.w;
#pragma unroll
    for (int o = 32; o > 0; o >>= 1) { s += __shfl_xor(s, o); sq += __shfl_xor(sq, o); }
    __shared__ float ps[4], pq[4];
    int wid = t >> 6, lane = t & 63;
    if (lane == 0) { ps[wid] = s; pq[wid] = sq; }
    __syncthreads();
    s = ps[0] + ps[1] + ps[2] + ps[3];
    sq = pq[0] + pq[1] + pq[2] + pq[3];
    float mu = s * (1.0f / CDIM);
    float var = sq * (1.0f / CDIM) - mu * mu;
    float rstd = rsqrtf(var + 1e-5f);
    float4 wv = ((const float4*)w)[t];
    union { u16 h[4]; uint2 u; } pk;
    pk.h[0] = f2bu((v.x - mu) * rstd * wv.x);
    pk.h[1] = f2bu((v.y - mu) * rstd * wv.y);
    pk.h[2] = f2bu((v.z - mu) * rstd * wv.z);
    pk.h[3] = f2bu((v.w - mu) * rstd * wv.w);
    ((uint2*)(out + (size_t)row * CDIM))[t] = pk.u;
}

// ---------------- GEMM: C[M,N] = A[M,K](bf16) * Bt[N,K](bf16)^T + epilogue ------
// EPI 0: -> bf16     1: +res(f32) -> f32     2: +bias, relu -> bf16
// EPI 3: +bias +res(f32) -> f32
template <int EPI>
__global__ __launch_bounds__(256) void gemm_bt(const u16* __restrict__ A,
                                               const u16* __restrict__ Bt,
                                               void* __restrict__ Cout,
                                               const float* __restrict__ bias,
                                               const float* __restrict__ res,
                                               int M, int N, int K) {
    __shared__ u16 Al[128 * 32];
    __shared__ u16 Bl[128 * 32];
    int tid = threadIdx.x;
    int lane = tid & 63, wid = tid >> 6;
    int wr = wid >> 1, wc = wid & 1;
    int lr = lane & 15, lk = lane >> 4;
    int m0 = blockIdx.y * 128, n0 = blockIdx.x * 128;

    f32x4 acc[4][4];
#pragma unroll
    for (int i = 0; i < 4; ++i)
#pragma unroll
        for (int j = 0; j < 4; ++j) acc[i][j] = (f32x4){0.f, 0.f, 0.f, 0.f};

    for (int k0 = 0; k0 < K; k0 += 32) {
        __syncthreads();
#pragma unroll
        for (int i = 0; i < 2; ++i) {
            int cb = (wid * 2 + i) * 64;       // wave-uniform chunk base
            int c = cb + lane;                 // 16B chunk id: row = c>>2, kchunk = c&3
            int r = c >> 2, kc = c & 3;
            gload_lds16(A + (size_t)(m0 + r) * K + k0 + kc * 8, Al + cb * 8);
            gload_lds16(Bt + (size_t)(n0 + r) * K + k0 + kc * 8, Bl + cb * 8);
        }
        __syncthreads();
        s16x8 af[4], bfr[4];
#pragma unroll
        for (int mi = 0; mi < 4; ++mi)
            af[mi] = *(const s16x8*)(Al + (wr * 64 + mi * 16 + lr) * 32 + lk * 8);
#pragma unroll
        for (int ni = 0; ni < 4; ++ni)
            bfr[ni] = *(const s16x8*)(Bl + (wc * 64 + ni * 16 + lr) * 32 + lk * 8);
#pragma unroll
        for (int mi = 0; mi < 4; ++mi)
#pragma unroll
            for (int ni = 0; ni < 4; ++ni)
                acc[mi][ni] = __builtin_amdgcn_mfma_f32_16x16x32_bf16(
                    af[mi], bfr[ni], acc[mi][ni], 0, 0, 0);
    }

#pragma unroll
    for (int mi = 0; mi < 4; ++mi) {
#pragma unroll
        for (int ni = 0; ni < 4; ++ni) {
            int col = n0 + wc * 64 + ni * 16 + lr;
#pragma unroll
            for (int r = 0; r < 4; ++r) {
                int row = m0 + wr * 64 + mi * 16 + lk * 4 + r;
                float v = acc[mi][ni][r];
                size_t idx = (size_t)row * N + col;
                if constexpr (EPI == 0) {
                    ((u16*)Cout)[idx] = f2bu(v);
                } else if constexpr (EPI == 1) {
                    ((float*)Cout)[idx] = res[idx] + v;
                } else if constexpr (EPI == 2) {
                    ((u16*)Cout)[idx] = f2bu(fmaxf(v + bias[col], 0.f));
                } else {
                    ((float*)Cout)[idx] = res[idx] + v + bias[col];
                }
            }
        }
    }
}

// ---------------- causal flash attention ----------------
// grid (T/128, B*H); 4 waves/block, each wave owns 32 q rows; kv tiles of 32.
__global__ __launch_bounds__(256) void attn_k(const u16* __restrict__ qkv,
                                              u16* __restrict__ y) {
    int qt = blockIdx.x;
    int bh = blockIdx.y;
    int b = bh >> 4, h = bh & 15;
    int tid = threadIdx.x, lane = tid & 63, wid = tid >> 6;
    int lr = lane & 15, lk = lane >> 4;
    int qbase = qt * 128 + wid * 32;
    const size_t rstr = 3 * CDIM;
    const u16* qp = qkv + (size_t)(b * TSEQ) * rstr + h * HDIM;
    const u16* kp = qp + CDIM;
    const u16* vp = qp + 2 * CDIM;

    __shared__ __align__(16) u16 Vt[64][40];       // V^T tile: [d][key]
    __shared__ __align__(16) u16 P[4][32][40];     // per-wave P tile

    s16x8 qf[2][2];
#pragma unroll
    for (int qs = 0; qs < 2; ++qs)
#pragma unroll
        for (int db = 0; db < 2; ++db)
            qf[qs][db] = *(const s16x8*)(qp + (size_t)(qbase + qs * 16 + lr) * rstr + db * 32 + lk * 8);

    f32x4 acc[2][4];
#pragma unroll
    for (int qs = 0; qs < 2; ++qs)
#pragma unroll
        for (int ds = 0; ds < 4; ++ds) acc[qs][ds] = (f32x4){0.f, 0.f, 0.f, 0.f};
    float mrow[2][4], lrow[2][4];
#pragma unroll
    for (int qs = 0; qs < 2; ++qs)
#pragma unroll
        for (int r = 0; r < 4; ++r) { mrow[qs][r] = -1e30f; lrow[qs][r] = 0.f; }

    int kvend = qt * 128 + 128;
    for (int kv0 = 0; kv0 < kvend; kv0 += 32) {
        __syncthreads();
        {   // stage V^T cooperatively: 256 threads x 8 elems
            int key = tid >> 3, d0 = (tid & 7) * 8;
            s16x8 vv = *(const s16x8*)(vp + (size_t)(kv0 + key) * rstr + d0);
#pragma unroll
            for (int j = 0; j < 8; ++j) Vt[d0 + j][key] = ((const u16*)&vv)[j];
        }
        __syncthreads();
        if (kv0 <= qbase) {   // wave-uniform causal skip
            s16x8 kf[2][2];
#pragma unroll
            for (int ks = 0; ks < 2; ++ks)
#pragma unroll
                for (int db = 0; db < 2; ++db)
                    kf[ks][db] = *(const s16x8*)(kp + (size_t)(kv0 + ks * 16 + lr) * rstr + db * 32 + lk * 8);
            f32x4 s[2][2];
#pragma unroll
            for (int qs = 0; qs < 2; ++qs)
#pragma unroll
                for (int ks = 0; ks < 2; ++ks) {
                    f32x4 z = (f32x4){0.f, 0.f, 0.f, 0.f};
                    z = __builtin_amdgcn_mfma_f32_16x16x32_bf16(qf[qs][0], kf[ks][0], z, 0, 0, 0);
                    s[qs][ks] = __builtin_amdgcn_mfma_f32_16x16x32_bf16(qf[qs][1], kf[ks][1], z, 0, 0, 0);
                }
            float scr[2][4];
#pragma unroll
            for (int qs = 0; qs < 2; ++qs) {
                float pm[4] = {-1e30f, -1e30f, -1e30f, -1e30f};
#pragma unroll
                for (int ks = 0; ks < 2; ++ks)
#pragma unroll
                    for (int r = 0; r < 4; ++r) {
                        int row = qbase + qs * 16 + lk * 4 + r;
                        int col = kv0 + ks * 16 + lr;
                        float v = s[qs][ks][r] * 0.125f;
                        v = (col > row) ? -1e30f : v;
                        s[qs][ks][r] = v;
                        pm[r] = fmaxf(pm[r], v);
                    }
                float rsum[4] = {0.f, 0.f, 0.f, 0.f};
#pragma unroll
                for (int r = 0; r < 4; ++r) {
#pragma unroll
                    for (int m = 1; m < 16; m <<= 1) pm[r] = fmaxf(pm[r], __shfl_xor(pm[r], m));
                    float mn = fmaxf(mrow[qs][r], pm[r]);
                    scr[qs][r] = __expf(mrow[qs][r] - mn);
                    mrow[qs][r] = mn;
                }
#pragma unroll
                for (int ks = 0; ks < 2; ++ks)
#pragma unroll
                    for (int r = 0; r < 4; ++r) {
                        float p = __expf(s[qs][ks][r] - mrow[qs][r]);
                        s[qs][ks][r] = p;
                        rsum[r] += p;
                    }
#pragma unroll
                for (int r = 0; r < 4; ++r) {
#pragma unroll
                    for (int m = 1; m < 16; m <<= 1) rsum[r] += __shfl_xor(rsum[r], m);
                    lrow[qs][r] = lrow[qs][r] * scr[qs][r] + rsum[r];
                }
#pragma unroll
                for (int ds = 0; ds < 4; ++ds)
#pragma unroll
                    for (int r = 0; r < 4; ++r) acc[qs][ds][r] *= scr[qs][r];
#pragma unroll
                for (int ks = 0; ks < 2; ++ks)
#pragma unroll
                    for (int r = 0; r < 4; ++r)
                        P[wid][qs * 16 + lk * 4 + r][ks * 16 + lr] = f2bu(s[qs][ks][r]);
            }
            asm volatile("s_waitcnt lgkmcnt(0)" ::: "memory");
            s16x8 pa[2], vb[4];
#pragma unroll
            for (int qs = 0; qs < 2; ++qs)
                pa[qs] = *(const s16x8*)&P[wid][qs * 16 + lr][lk * 8];
#pragma unroll
            for (int ds = 0; ds < 4; ++ds)
                vb[ds] = *(const s16x8*)&Vt[ds * 16 + lr][lk * 8];
#pragma unroll
            for (int qs = 0; qs < 2; ++qs)
#pragma unroll
                for (int ds = 0; ds < 4; ++ds)
                    acc[qs][ds] = __builtin_amdgcn_mfma_f32_16x16x32_bf16(pa[qs], vb[ds], acc[qs][ds], 0, 0, 0);
        }
    }
#pragma unroll
    for (int qs = 0; qs < 2; ++qs)
#pragma unroll
        for (int ds = 0; ds < 4; ++ds)
#pragma unroll
            for (int r = 0; r < 4; ++r) {
                int row = qbase + qs * 16 + lk * 4 + r;
                y[(size_t)(b * TSEQ + row) * CDIM + h * HDIM + ds * 16 + lr] =
                    f2bu(acc[qs][ds][r] / lrow[qs][r]);
            }
}

extern "C" void kernel_launch(void* const* d_in, const int* in_sizes, int n_in,
                              void* d_out, int out_size, void* d_ws, size_t ws_size,
                              hipStream_t stream) {
    const float* x      = (const float*)d_in[0];
    const float* ln1_w  = (const float*)d_in[1];
    const float* w_attn = (const float*)d_in[2];
    const float* w_proj = (const float*)d_in[3];
    const float* ln2_w  = (const float*)d_in[4];
    const float* w_fc1  = (const float*)d_in[5];
    const float* b_fc1  = (const float*)d_in[6];
    const float* w_fc2  = (const float*)d_in[7];
    const float* b_fc2  = (const float*)d_in[8];
    float* out = (float*)d_out;
    char* ws = (char*)d_ws;

    // ws layout (bytes): total 136 MB
    u16*   wT_attn = (u16*)(ws + 0);            // [3072][1024] bf16, 6.0 MB
    u16*   wT_proj = (u16*)(ws + 6291456);      // [1024][1024], 2 MB
    u16*   wT_fc1  = (u16*)(ws + 8388608);      // [4096][1024], 8 MB
    u16*   wT_fc2  = (u16*)(ws + 16777216);     // [1024][4096], 8 MB
    u16*   h       = (u16*)(ws + 25165824);     // [8192][1024] (ln1 out, later ln2 out)
    u16*   qkvb    = (u16*)(ws + 41943040);     // [8192][3072]
    u16*   yb      = (u16*)(ws + 92274688);     // [8192][1024]
    float* x1      = (float*)(ws + 109051904);  // [8192][1024] f32
    u16*   h3      = (u16*)(ws + 41943040);     // [8192][4096] reuses qkv+y region

    twb_k<<<dim3(3072 / 32, 1024 / 32), 256, 0, stream>>>(w_attn, wT_attn, 1024, 3072);
    twb_k<<<dim3(1024 / 32, 1024 / 32), 256, 0, stream>>>(w_proj, wT_proj, 1024, 1024);
    twb_k<<<dim3(4096 / 32, 1024 / 32), 256, 0, stream>>>(w_fc1, wT_fc1, 1024, 4096);
    twb_k<<<dim3(1024 / 32, 4096 / 32), 256, 0, stream>>>(w_fc2, wT_fc2, 4096, 1024);

    ln_k<<<8192, 256, 0, stream>>>(x, ln1_w, h);
    gemm_bt<0><<<dim3(3072 / 128, 8192 / 128), 256, 0, stream>>>(h, wT_attn, qkvb, nullptr, nullptr, 8192, 3072, 1024);
    attn_k<<<dim3(TSEQ / 128, NBATCH * NHEAD), 256, 0, stream>>>(qkvb, yb);
    gemm_bt<1><<<dim3(1024 / 128, 8192 / 128), 256, 0, stream>>>(yb, wT_proj, x1, nullptr, x, 8192, 1024, 1024);
    ln_k<<<8192, 256, 0, stream>>>(x1, ln2_w, h);
    gemm_bt<2><<<dim3(4096 / 128, 8192 / 128), 256, 0, stream>>>(h, wT_fc1, h3, b_fc1, nullptr, 8192, 4096, 1024);
    gemm_bt<3><<<dim3(1024 / 128, 8192 / 128), 256, 0, stream>>>(h3, wT_fc2, out, b_fc2, x1, 8192, 1024, 4096);
}

// Round 2
// 620.947 us; speedup vs baseline: 1.3966x; 1.3966x over previous
//
#include <hip/hip_runtime.h>
#include <cstdint>

// Transformer block, bf16 MFMA implementation.
// R1: attention rewritten — paired q-tiles (uniform work), swapped QK^T with
// in-register softmax, V^T produced by QKV-GEMM epilogue, K/V^T staged via
// XOR-pre-swizzled global_load_lds (conflict-free ds_read_b128), 2-phase
// counted-vmcnt pipeline.

#define CDIM 1024
#define TSEQ 2048
#define NBATCH 4
#define NHEAD 16
#define HDIM 64
#define FDIM 4096

typedef unsigned short u16;
typedef __attribute__((ext_vector_type(8))) short s16x8;   // 8 bf16 in 4 VGPRs
typedef __attribute__((ext_vector_type(4))) float f32x4;

__device__ __forceinline__ u16 f2bu(float f) {             // f32 -> bf16 bits, RNE
    uint32_t u = __builtin_bit_cast(uint32_t, f);
    uint32_t r = (u + 0x7FFFu + ((u >> 16) & 1u)) >> 16;
    return (u16)r;
}

__device__ __forceinline__ uint32_t cvtpk(float lo, float hi) {  // packed bf16 (lo->bits0..15)
    uint32_t r;
    asm("v_cvt_pk_bf16_f32 %0, %1, %2" : "=v"(r) : "v"(lo), "v"(hi));
    return r;
}

typedef __attribute__((address_space(3))) unsigned int lds_u32;
typedef __attribute__((address_space(1))) const unsigned int glb_u32;
__device__ __forceinline__ void gload_lds16(const void* g, void* l) {
    // async global->LDS, 16B per lane; LDS dest = uniform base + lane*16
    __builtin_amdgcn_global_load_lds((glb_u32*)g, (lds_u32*)l, 16, 0, 0);
}

// ---------------- weight fp32 [K][N] -> bf16 transposed [N][K] ----------------
__global__ __launch_bounds__(256) void twb_k(const float* __restrict__ in,
                                             u16* __restrict__ out, int K, int N) {
    __shared__ float tile[32][33];
    int n0 = blockIdx.x * 32, k0 = blockIdx.y * 32;
    int tx = threadIdx.x & 31, ty = threadIdx.x >> 5;
#pragma unroll
    for (int i = 0; i < 32; i += 8)
        tile[ty + i][tx] = in[(size_t)(k0 + ty + i) * N + n0 + tx];
    __syncthreads();
#pragma unroll
    for (int i = 0; i < 32; i += 8)
        out[(size_t)(n0 + ty + i) * K + k0 + tx] = f2bu(tile[tx][ty + i]);
}

// ---------------- layernorm (f32 in, bf16 out), one row per block ----------------
__global__ __launch_bounds__(256) void ln_k(const float* __restrict__ x,
                                            const float* __restrict__ w,
                                            u16* __restrict__ out) {
    int row = blockIdx.x;
    int t = threadIdx.x;
    const float4* xr = (const float4*)(x + (size_t)row * CDIM);
    float4 v = xr[t];
    float s = v.x + v.y + v.z + v.w;
    float sq = v.x * v.x + v.y * v.y + v.z * v.z + v.w * v.w;
#pragma unroll
    for (int o = 32; o > 0; o >>= 1) { s += __shfl_xor(s, o); sq += __shfl_xor(sq, o); }
    __shared__ float ps[4], pq[4];
    int wid = t >> 6, lane = t & 63;
    if (lane == 0) { ps[wid] = s; pq[wid] = sq; }
    __syncthreads();
    s = ps[0] + ps[1] + ps[2] + ps[3];
    sq = pq[0] + pq[1] + pq[2] + pq[3];
    float mu = s * (1.0f / CDIM);
    float var = sq * (1.0f / CDIM) - mu * mu;
    float rstd = rsqrtf(var + 1e-5f);
    float4 wv = ((const float4*)w)[t];
    union { u16 h[4]; uint2 u; } pk;
    pk.h[0] = f2bu((v.x - mu) * rstd * wv.x);
    pk.h[1] = f2bu((v.y - mu) * rstd * wv.y);
    pk.h[2] = f2bu((v.z - mu) * rstd * wv.z);
    pk.h[3] = f2bu((v.w - mu) * rstd * wv.w);
    ((uint2*)(out + (size_t)row * CDIM))[t] = pk.u;
}

// ---------------- GEMM: C[M,N] = A[M,K](bf16) * Bt[N,K](bf16)^T + epilogue ------
// EPI 0: QKV: cols<2048 -> bf16 C; cols>=2048 (V) -> vT[bh][d][t] bf16
// EPI 1: +res(f32) -> f32     2: +bias, relu -> bf16     3: +bias +res(f32) -> f32
template <int EPI>
__global__ __launch_bounds__(256) void gemm_bt(const u16* __restrict__ A,
                                               const u16* __restrict__ Bt,
                                               void* __restrict__ Cout,
                                               u16* __restrict__ Vout,
                                               const float* __restrict__ bias,
                                               const float* __restrict__ res,
                                               int M, int N, int K) {
    __shared__ u16 Al[128 * 32];
    __shared__ u16 Bl[128 * 32];
    int tid = threadIdx.x;
    int lane = tid & 63, wid = tid >> 6;
    int wr = wid >> 1, wc = wid & 1;
    int lr = lane & 15, lk = lane >> 4;
    int m0 = blockIdx.y * 128, n0 = blockIdx.x * 128;

    f32x4 acc[4][4];
#pragma unroll
    for (int i = 0; i < 4; ++i)
#pragma unroll
        for (int j = 0; j < 4; ++j) acc[i][j] = (f32x4){0.f, 0.f, 0.f, 0.f};

    for (int k0 = 0; k0 < K; k0 += 32) {
        __syncthreads();
#pragma unroll
        for (int i = 0; i < 2; ++i) {
            int cb = (wid * 2 + i) * 64;
            int c = cb + lane;
            int r = c >> 2, kc = c & 3;
            gload_lds16(A + (size_t)(m0 + r) * K + k0 + kc * 8, Al + cb * 8);
            gload_lds16(Bt + (size_t)(n0 + r) * K + k0 + kc * 8, Bl + cb * 8);
        }
        __syncthreads();
        s16x8 af[4], bfr[4];
#pragma unroll
        for (int mi = 0; mi < 4; ++mi)
            af[mi] = *(const s16x8*)(Al + (wr * 64 + mi * 16 + lr) * 32 + lk * 8);
#pragma unroll
        for (int ni = 0; ni < 4; ++ni)
            bfr[ni] = *(const s16x8*)(Bl + (wc * 64 + ni * 16 + lr) * 32 + lk * 8);
#pragma unroll
        for (int mi = 0; mi < 4; ++mi)
#pragma unroll
            for (int ni = 0; ni < 4; ++ni)
                acc[mi][ni] = __builtin_amdgcn_mfma_f32_16x16x32_bf16(
                    af[mi], bfr[ni], acc[mi][ni], 0, 0, 0);
    }

#pragma unroll
    for (int mi = 0; mi < 4; ++mi) {
#pragma unroll
        for (int ni = 0; ni < 4; ++ni) {
            int col = n0 + wc * 64 + ni * 16 + lr;
#pragma unroll
            for (int r = 0; r < 4; ++r) {
                int row = m0 + wr * 64 + mi * 16 + lk * 4 + r;
                float v = acc[mi][ni][r];
                size_t idx = (size_t)row * N + col;
                if constexpr (EPI == 0) {
                    if (col < 2048) {
                        ((u16*)Cout)[idx] = f2bu(v);
                    } else {
                        int bb = row >> 11, tt = row & 2047, cc = col - 2048;
                        Vout[((size_t)(bb * 16 + (cc >> 6)) * 64 + (cc & 63)) * 2048 + tt] = f2bu(v);
                    }
                } else if constexpr (EPI == 1) {
                    ((float*)Cout)[idx] = res[idx] + v;
                } else if constexpr (EPI == 2) {
                    ((u16*)Cout)[idx] = f2bu(fmaxf(v + bias[col], 0.f));
                } else {
                    ((float*)Cout)[idx] = res[idx] + v + bias[col];
                }
            }
        }
    }
}

// ---------------- causal flash attention (R1 rewrite) ----------------
// grid (T/256, B*H): block p handles q-tiles p and 15-p (uniform 17 kv-tiles).
// 4 waves/block, wave owns 32 q rows. KVBLK=128. Swapped QK^T: S^T=mfma(K,Q),
// q lane-local (col=lr) -> in-register softmax. PV: O^T = mfma(V^T, P).
__global__ __launch_bounds__(256) void attn_k(const u16* __restrict__ qkv,
                                              const u16* __restrict__ vT,
                                              u16* __restrict__ y) {
    int pidx = blockIdx.x;
    int bh = blockIdx.y;
    int b = bh >> 4, h = bh & 15;
    int tid = threadIdx.x, lane = tid & 63, wid = tid >> 6;
    int lr = lane & 15, lk = lane >> 4;

    __shared__ u16 Kl[2][8192];   // [128 k][8 ch of 16B, XOR-swizzled]
    __shared__ u16 Vl[2][8192];   // [64 d][16 ch of 16B, low3 XOR-swizzled]

    const u16* qkp = qkv + (size_t)(b * TSEQ) * 3072 + h * HDIM;
    const u16* kkp = qkp + CDIM;
    const u16* vtp = vT + (size_t)bh * HDIM * TSEQ;

    auto STAGE = [&](int buf, int kv0) {
#pragma unroll
        for (int c = 0; c < 4; ++c) {
            int s = c * 256 + wid * 64 + lane;
            int kr = s >> 3, kc = s & 7;
            int gkc = kc ^ (kr & 7);
            gload_lds16(kkp + (size_t)(kv0 + kr) * 3072 + gkc * 8,
                        &Kl[buf][(size_t)(c * 256 + wid * 64) * 8]);
            int vd = s >> 4, vc = s & 15;
            int gvc = (vc & 8) | ((vc ^ vd) & 7);
            gload_lds16(vtp + (size_t)vd * TSEQ + kv0 + gvc * 8,
                        &Vl[buf][(size_t)(c * 256 + wid * 64) * 8]);
        }
    };

    auto qtile = [&](int qt) {
        int qbase = qt * 128 + wid * 32;
        int qend = qbase + 31;
        s16x8 qf[2][2];
#pragma unroll
        for (int qs = 0; qs < 2; ++qs)
#pragma unroll
            for (int db = 0; db < 2; ++db)
                qf[qs][db] = *(const s16x8*)(qkp +
                    (size_t)(qbase + qs * 16 + lr) * 3072 + db * 32 + lk * 8);
        f32x4 acc[2][4];
#pragma unroll
        for (int qs = 0; qs < 2; ++qs)
#pragma unroll
            for (int ds = 0; ds < 4; ++ds) acc[qs][ds] = (f32x4){0.f, 0.f, 0.f, 0.f};
        float mrun[2] = {-1e30f, -1e30f};
        float lrun[2] = {0.f, 0.f};

        int nt = qt + 1;
        STAGE(0, 0);
        for (int t = 0; t < nt; ++t) {
            int cur = t & 1;
            int kv0 = t * 128;
            if (t + 1 < nt) {
                STAGE(cur ^ 1, (t + 1) * 128);
                asm volatile("s_waitcnt vmcnt(8)" ::: "memory");
            } else {
                asm volatile("s_waitcnt vmcnt(0)" ::: "memory");
            }
            __builtin_amdgcn_s_barrier();
            asm volatile("" ::: "memory");

            const u16* Kb = &Kl[cur][0];
            const u16* Vb = &Vl[cur][0];

            // ---- S^T = K·Q^T (row=k, col=q) ----
            f32x4 st[8][2];
#pragma unroll
            for (int ks = 0; ks < 8; ++ks)
#pragma unroll
                for (int qs = 0; qs < 2; ++qs)
                    st[ks][qs] = (f32x4){-1e30f, -1e30f, -1e30f, -1e30f};
            __builtin_amdgcn_s_setprio(1);
#pragma unroll
            for (int ks = 0; ks < 8; ++ks) {
                if (kv0 + ks * 16 <= qend) {   // wave-uniform causal subtile skip
                    s16x8 kf0 = *(const s16x8*)(Kb + (ks * 16 + lr) * 64 + ((lk ^ (lr & 7)) * 8));
                    s16x8 kf1 = *(const s16x8*)(Kb + (ks * 16 + lr) * 64 + (((4 + lk) ^ (lr & 7)) * 8));
#pragma unroll
                    for (int qs = 0; qs < 2; ++qs) {
                        f32x4 z = (f32x4){0.f, 0.f, 0.f, 0.f};
                        z = __builtin_amdgcn_mfma_f32_16x16x32_bf16(kf0, qf[qs][0], z, 0, 0, 0);
                        st[ks][qs] = __builtin_amdgcn_mfma_f32_16x16x32_bf16(kf1, qf[qs][1], z, 0, 0, 0);
                    }
                }
            }
            __builtin_amdgcn_s_setprio(0);

            if (kv0 + 127 > qbase) {   // diagonal tile: per-element causal mask
#pragma unroll
                for (int ks = 0; ks < 8; ++ks)
#pragma unroll
                    for (int qs = 0; qs < 2; ++qs)
#pragma unroll
                        for (int r = 0; r < 4; ++r) {
                            int k = kv0 + ks * 16 + lk * 4 + r;
                            int q = qbase + qs * 16 + lr;
                            if (k > q) st[ks][qs][r] = -1e30f;
                        }
            }

            // ---- online softmax (q = lr lane-local; scale 0.125 folded in exp) ----
            uint32_t w[2][8][2];
#pragma unroll
            for (int qs = 0; qs < 2; ++qs) {
                float pmax = -1e30f;
#pragma unroll
                for (int ks = 0; ks < 8; ++ks) {
                    float a = fmaxf(fmaxf(st[ks][qs][0], st[ks][qs][1]),
                                    fmaxf(st[ks][qs][2], st[ks][qs][3]));
                    pmax = fmaxf(pmax, a);
                }
                pmax = fmaxf(pmax, __shfl_xor(pmax, 16));
                pmax = fmaxf(pmax, __shfl_xor(pmax, 32));
                float mnew = fmaxf(mrun[qs], pmax);
                float scale = __expf((mrun[qs] - mnew) * 0.125f);
                mrun[qs] = mnew;
                float psum = 0.f;
#pragma unroll
                for (int ks = 0; ks < 8; ++ks) {
#pragma unroll
                    for (int r = 0; r < 4; ++r) {
                        float pv = __expf((st[ks][qs][r] - mnew) * 0.125f);
                        st[ks][qs][r] = pv;
                        psum += pv;
                    }
                    w[qs][ks][0] = cvtpk(st[ks][qs][0], st[ks][qs][1]);
                    w[qs][ks][1] = cvtpk(st[ks][qs][2], st[ks][qs][3]);
                }
                psum += __shfl_xor(psum, 16);
                psum += __shfl_xor(psum, 32);
                lrun[qs] = lrun[qs] * scale + psum;
#pragma unroll
                for (int ds = 0; ds < 4; ++ds)
#pragma unroll
                    for (int r = 0; r < 4; ++r) acc[qs][ds][r] *= scale;
            }

            // ---- PV: acc(O^T) += mfma(V^T rows, P rows) ----
            int A = lr + ((lane & 16) ? 32 : 0);
            bool hi = (lane & 32) != 0;
#pragma unroll
            for (int kh = 0; kh < 4; ++kh) {
                if (kv0 + kh * 32 <= qend) {   // wave-uniform
                    s16x8 vtf[4];
#pragma unroll
                    for (int ds = 0; ds < 4; ++ds) {
                        int ch = kh * 4 + lk;
                        int chs = (ch & 8) | ((ch ^ (lr & 7)) & 7);
                        vtf[ds] = *(const s16x8*)(Vb + (ds * 16 + lr) * 128 + chs * 8);
                    }
                    __builtin_amdgcn_s_setprio(1);
#pragma unroll
                    for (int qs = 0; qs < 2; ++qs) {
                        uint32_t p00 = (uint32_t)__shfl((int)w[qs][2 * kh][0], A);
                        uint32_t p01 = (uint32_t)__shfl((int)w[qs][2 * kh][1], A);
                        uint32_t p10 = (uint32_t)__shfl((int)w[qs][2 * kh + 1][0], A);
                        uint32_t p11 = (uint32_t)__shfl((int)w[qs][2 * kh + 1][1], A);
                        uint32_t q00 = (uint32_t)__shfl((int)w[qs][2 * kh][0], A + 16);
                        uint32_t q01 = (uint32_t)__shfl((int)w[qs][2 * kh][1], A + 16);
                        uint32_t q10 = (uint32_t)__shfl((int)w[qs][2 * kh + 1][0], A + 16);
                        uint32_t q11 = (uint32_t)__shfl((int)w[qs][2 * kh + 1][1], A + 16);
                        union { uint32_t u[4]; s16x8 v; } pf;
                        pf.u[0] = hi ? p10 : p00;
                        pf.u[1] = hi ? p11 : p01;
                        pf.u[2] = hi ? q10 : q00;
                        pf.u[3] = hi ? q11 : q01;
#pragma unroll
                        for (int ds = 0; ds < 4; ++ds)
                            acc[qs][ds] = __builtin_amdgcn_mfma_f32_16x16x32_bf16(
                                vtf[ds], pf.v, acc[qs][ds], 0, 0, 0);
                    }
                    __builtin_amdgcn_s_setprio(0);
                }
            }
            asm volatile("" ::: "memory");
            __builtin_amdgcn_s_barrier();
            asm volatile("" ::: "memory");
        }

        // ---- epilogue: acc is O^T (row=d=lk*4+r, col=q=lr) ----
        float rl[2] = {1.f / lrun[0], 1.f / lrun[1]};
#pragma unroll
        for (int qs = 0; qs < 2; ++qs) {
            int q = qbase + qs * 16 + lr;
            u16* yr = y + (size_t)(b * TSEQ + q) * CDIM + h * HDIM;
#pragma unroll
            for (int ds = 0; ds < 4; ++ds)
#pragma unroll
                for (int r = 0; r < 4; ++r)
                    yr[ds * 16 + lk * 4 + r] = f2bu(acc[qs][ds][r] * rl[qs]);
        }
    };

    qtile(pidx);
    qtile(15 - pidx);
}

extern "C" void kernel_launch(void* const* d_in, const int* in_sizes, int n_in,
                              void* d_out, int out_size, void* d_ws, size_t ws_size,
                              hipStream_t stream) {
    (void)in_sizes; (void)n_in; (void)out_size; (void)ws_size;
    const float* x      = (const float*)d_in[0];
    const float* ln1_w  = (const float*)d_in[1];
    const float* w_attn = (const float*)d_in[2];
    const float* w_proj = (const float*)d_in[3];
    const float* ln2_w  = (const float*)d_in[4];
    const float* w_fc1  = (const float*)d_in[5];
    const float* b_fc1  = (const float*)d_in[6];
    const float* w_fc2  = (const float*)d_in[7];
    const float* b_fc2  = (const float*)d_in[8];
    float* out = (float*)d_out;
    char* ws = (char*)d_ws;

    // ws layout (bytes), total 142.6 MB:
    u16*   wT_attn = (u16*)(ws + 0);            // [3072][1024] bf16, 6 MB
    u16*   wT_proj = (u16*)(ws + 6291456);      // [1024][1024], 2 MB
    u16*   wT_fc1  = (u16*)(ws + 8388608);      // [4096][1024], 8 MB
    u16*   wT_fc2  = (u16*)(ws + 16777216);     // [1024][4096], 8 MB
    u16*   h       = (u16*)(ws + 25165824);     // [8192][1024] (ln1 out, later ln2 out)
    u16*   qkvb    = (u16*)(ws + 41943040);     // [8192][3072] (V third unused)
    u16*   yb      = (u16*)(ws + 92274688);     // [8192][1024]
    float* x1      = (float*)(ws + 109051904);  // [8192][1024] f32 (live from proj on)
    u16*   vTb     = (u16*)(ws + 109051904);    // [64 bh][64 d][2048 t] bf16, 16 MB
                                                // aliases x1: vT dead before proj writes x1
    u16*   h3      = (u16*)(ws + 41943040);     // [8192][4096] reuses qkv region

    twb_k<<<dim3(3072 / 32, 1024 / 32), 256, 0, stream>>>(w_attn, wT_attn, 1024, 3072);
    twb_k<<<dim3(1024 / 32, 1024 / 32), 256, 0, stream>>>(w_proj, wT_proj, 1024, 1024);
    twb_k<<<dim3(4096 / 32, 1024 / 32), 256, 0, stream>>>(w_fc1, wT_fc1, 1024, 4096);
    twb_k<<<dim3(1024 / 32, 4096 / 32), 256, 0, stream>>>(w_fc2, wT_fc2, 4096, 1024);

    ln_k<<<8192, 256, 0, stream>>>(x, ln1_w, h);
    gemm_bt<0><<<dim3(3072 / 128, 8192 / 128), 256, 0, stream>>>(h, wT_attn, qkvb, vTb, nullptr, nullptr, 8192, 3072, 1024);
    attn_k<<<dim3(8, NBATCH * NHEAD), 256, 0, stream>>>(qkvb, vTb, yb);
    gemm_bt<1><<<dim3(1024 / 128, 8192 / 128), 256, 0, stream>>>(yb, wT_proj, x1, nullptr, nullptr, x, 8192, 1024, 1024);
    ln_k<<<8192, 256, 0, stream>>>(x1, ln2_w, h);
    gemm_bt<2><<<dim3(4096 / 128, 8192 / 128), 256, 0, stream>>>(h, wT_fc1, h3, nullptr, b_fc1, nullptr, 8192, 4096, 1024);
    gemm_bt<3><<<dim3(1024 / 128, 8192 / 128), 256, 0, stream>>>(h3, wT_fc2, out, nullptr, b_fc2, x1, 8192, 1024, 4096);
}

// Round 6
// 614.475 us; speedup vs baseline: 1.4113x; 1.0105x over previous
//
#include <hip/hip_runtime.h>
#include <cstdint>

// Transformer block, bf16 MFMA implementation.
// R5 = R4 with the fc2 gemm_bt<3> call-site arity fixed (stray nullptr removed).
// QKV/FC1: 256^2 8-phase counted-vmcnt kernel (T1+T2+T3/T4+T5).
// proj/fc2: 128^2 kernel + XCD swizzle. Attention: R1 structure.

#define CDIM 1024
#define TSEQ 2048
#define NBATCH 4
#define NHEAD 16
#define HDIM 64
#define FDIM 4096

typedef unsigned short u16;
typedef __attribute__((ext_vector_type(8))) short s16x8;   // 8 bf16 in 4 VGPRs
typedef __attribute__((ext_vector_type(4))) float f32x4;

__device__ __forceinline__ u16 f2bu(float f) {             // f32 -> bf16 bits, RNE
    uint32_t u = __builtin_bit_cast(uint32_t, f);
    uint32_t r = (u + 0x7FFFu + ((u >> 16) & 1u)) >> 16;
    return (u16)r;
}

__device__ __forceinline__ uint32_t cvtpk(float lo, float hi) {  // packed bf16
    uint32_t r;
    asm("v_cvt_pk_bf16_f32 %0, %1, %2" : "=v"(r) : "v"(lo), "v"(hi));
    return r;
}

typedef __attribute__((address_space(3))) unsigned int lds_u32;
typedef __attribute__((address_space(1))) const unsigned int glb_u32;
__device__ __forceinline__ void gload_lds16(const void* g, void* l) {
    // async global->LDS, 16B per lane; LDS dest = uniform base + lane*16
    __builtin_amdgcn_global_load_lds((glb_u32*)g, (lds_u32*)l, 16, 0, 0);
}

#define FENCE() asm volatile("" ::: "memory")

// ---------------- weight fp32 [K][N] -> bf16 transposed [N][K] ----------------
__global__ __launch_bounds__(256) void twb_k(const float* __restrict__ in,
                                             u16* __restrict__ out, int K, int N) {
    __shared__ float tile[32][33];
    int n0 = blockIdx.x * 32, k0 = blockIdx.y * 32;
    int tx = threadIdx.x & 31, ty = threadIdx.x >> 5;
#pragma unroll
    for (int i = 0; i < 32; i += 8)
        tile[ty + i][tx] = in[(size_t)(k0 + ty + i) * N + n0 + tx];
    __syncthreads();
#pragma unroll
    for (int i = 0; i < 32; i += 8)
        out[(size_t)(n0 + ty + i) * K + k0 + tx] = f2bu(tile[tx][ty + i]);
}

// ---------------- layernorm (f32 in, bf16 out), one row per block ----------------
__global__ __launch_bounds__(256) void ln_k(const float* __restrict__ x,
                                            const float* __restrict__ w,
                                            u16* __restrict__ out) {
    int row = blockIdx.x;
    int t = threadIdx.x;
    const float4* xr = (const float4*)(x + (size_t)row * CDIM);
    float4 v = xr[t];
    float s = v.x + v.y + v.z + v.w;
    float sq = v.x * v.x + v.y * v.y + v.z * v.z + v.w * v.w;
#pragma unroll
    for (int o = 32; o > 0; o >>= 1) { s += __shfl_xor(s, o); sq += __shfl_xor(sq, o); }
    __shared__ float ps[4], pq[4];
    int wid = t >> 6, lane = t & 63;
    if (lane == 0) { ps[wid] = s; pq[wid] = sq; }
    __syncthreads();
    s = ps[0] + ps[1] + ps[2] + ps[3];
    sq = pq[0] + pq[1] + pq[2] + pq[3];
    float mu = s * (1.0f / CDIM);
    float var = sq * (1.0f / CDIM) - mu * mu;
    float rstd = rsqrtf(var + 1e-5f);
    float4 wv = ((const float4*)w)[t];
    union { u16 h[4]; uint2 u; } pk;
    pk.h[0] = f2bu((v.x - mu) * rstd * wv.x);
    pk.h[1] = f2bu((v.y - mu) * rstd * wv.y);
    pk.h[2] = f2bu((v.z - mu) * rstd * wv.z);
    pk.h[3] = f2bu((v.w - mu) * rstd * wv.w);
    ((uint2*)(out + (size_t)row * CDIM))[t] = pk.u;
}

// ================= 256^2 8-phase GEMM (QKV: EPI0, FC1: EPI2) =================
// C[M,N] = A[M,K] * Bt[N,K]^T, bf16 in, fp32 acc. NT = K/64 must be EVEN.
// EPI 0: cols<2048 -> bf16 C; cols>=2048 (V) -> vT[bh][d][t]
// EPI 2: +bias, relu -> bf16
template <int EPI>
__global__ __launch_bounds__(512, 2) void gemm8p(const u16* __restrict__ A,
                                                 const u16* __restrict__ Bt,
                                                 void* __restrict__ Cout,
                                                 u16* __restrict__ Vout,
                                                 const float* __restrict__ bias,
                                                 int M, int N, int K) {
    // [slot][op(A=0,B=1)][khalf][r2][8 slots x 8 u16]; 16KB per (slot,op,kh) = 128KB
    __shared__ __align__(16) u16 L[2][2][2][128][64];
    const int tid = threadIdx.x, lane = tid & 63, wid = tid >> 6;
    const int lr = lane & 15, lk = lane >> 4;
    const int wr = wid >> 2, wcn = wid & 3;
    // T1 XCD swizzle (nwg % 8 == 0 for all our launches)
    const int nbx = gridDim.x;
    const int nwg = nbx * gridDim.y;
    const int bid = blockIdx.y * nbx + blockIdx.x;
    const int swz = (bid & 7) * (nwg >> 3) + (bid >> 3);
    const int m0 = (swz / nbx) * 256, n0 = (swz % nbx) * 256;
    const int NT = K >> 6;

    auto STG = [&](int kt, int part, int kh) {
        const u16* src = part ? Bt : A;
        const int base0 = part ? n0 : m0;
        u16* dst = &L[kt & 1][part][kh][0][0];
#pragma unroll
        for (int i = 0; i < 2; ++i) {
            int t = i * 512 + tid;
            int r2 = t >> 3, se = t & 7;
            int s = se ^ (r2 & 7);                 // inverse swizzle on global src
            int row = 2 * r2 + (s >> 2), c = s & 3;
            gload_lds16(src + (size_t)(base0 + row) * K + kt * 64 + kh * 32 + c * 8,
                        dst + (size_t)(i * 512 + wid * 64) * 8);
        }
    };

    f32x4 acc[8][4];
#pragma unroll
    for (int i = 0; i < 8; ++i)
#pragma unroll
        for (int j = 0; j < 4; ++j) acc[i][j] = (f32x4){0.f, 0.f, 0.f, 0.f};

    // prologue: tile0 complete + tile1 k0 halves = 12 loads/wave; retire tile0-k0.
    STG(0, 0, 0); STG(0, 1, 0); STG(0, 0, 1); STG(0, 1, 1);
    STG(1, 0, 0); STG(1, 1, 0);
    asm volatile("s_waitcnt vmcnt(8)" ::: "memory");
    FENCE(); __builtin_amdgcn_s_barrier(); FENCE();

    const int se = (((lr & 1) << 2) | lk) ^ (lr >> 1);   // swizzled read slot
    const int rA0 = wr * 64 + (lr >> 1);                  // A r2 base (this wave)
    const int rB0 = wcn * 32 + (lr >> 1);                 // B r2 base

    s16x8 af[4], bf[4];

#define LDA(kh, ch) \
    { _Pragma("unroll") for (int q = 0; q < 4; ++q) \
        af[q] = *(const s16x8*)&L[slot][0][kh][rA0 + (ch) * 32 + q * 8][se * 8]; }
#define LDB(kh) \
    { _Pragma("unroll") for (int q = 0; q < 4; ++q) \
        bf[q] = *(const s16x8*)&L[slot][1][kh][rB0 + q * 8][se * 8]; }
#define MM(ch) \
    { __builtin_amdgcn_s_setprio(1); \
      _Pragma("unroll") for (int qm = 0; qm < 4; ++qm) \
      _Pragma("unroll") for (int ni = 0; ni < 4; ++ni) \
        acc[(ch) * 4 + qm][ni] = __builtin_amdgcn_mfma_f32_16x16x32_bf16( \
            af[qm], bf[ni], acc[(ch) * 4 + qm][ni], 0, 0, 0); \
      __builtin_amdgcn_s_setprio(0); }
#define BAR() { FENCE(); __builtin_amdgcn_s_barrier(); FENCE(); }
#define CKPT() asm volatile("s_waitcnt vmcnt(8)" ::: "memory")

    for (int j = 0; j < NT; ++j) {
        const int slot = j & 1;
        // wrapped stage targets: tail re-stages tile 0/1 (never read) so the
        // vmcnt(8) ledger stays in steady state — avoids tail race. NT even.
        const int jn1 = (j + 1 < NT) ? j + 1 : j + 1 - NT;
        const int jn2 = (j + 2 < NT) ? j + 2 : j + 2 - NT;
        // P1: C-half0 x k0
        LDA(0, 0); LDB(0);
        STG(jn1, 0, 1);
        BAR(); MM(0); BAR();
        // P2: C-half1 x k0
        LDA(0, 1);
        STG(jn1, 1, 1);
        CKPT();
        BAR(); MM(1); BAR();
        // P3: C-half0 x k1
        LDA(1, 0); LDB(1);
        STG(jn2, 0, 0);
        BAR(); MM(0); BAR();
        // P4: C-half1 x k1
        LDA(1, 1);
        STG(jn2, 1, 0);
        CKPT();
        BAR(); MM(1); BAR();
    }
#undef LDA
#undef LDB
#undef MM
#undef BAR
#undef CKPT

#pragma unroll
    for (int mi = 0; mi < 8; ++mi) {
#pragma unroll
        for (int ni = 0; ni < 4; ++ni) {
            int col = n0 + wcn * 64 + ni * 16 + lr;
#pragma unroll
            for (int r = 0; r < 4; ++r) {
                int row = m0 + wr * 128 + mi * 16 + lk * 4 + r;
                float v = acc[mi][ni][r];
                size_t idx = (size_t)row * N + col;
                if constexpr (EPI == 0) {
                    if (col < 2048) {
                        ((u16*)Cout)[idx] = f2bu(v);
                    } else {
                        int bb = row >> 11, tt = row & 2047, cc = col - 2048;
                        Vout[((size_t)(bb * 16 + (cc >> 6)) * 64 + (cc & 63)) * 2048 + tt] = f2bu(v);
                    }
                } else {
                    ((u16*)Cout)[idx] = f2bu(fmaxf(v + bias[col], 0.f));
                }
            }
        }
    }
}

// ---------------- 128^2 GEMM (proj: EPI1, fc2: EPI3) ----------------
// EPI 1: +res(f32) -> f32     3: +bias +res(f32) -> f32
template <int EPI>
__global__ __launch_bounds__(256) void gemm_bt(const u16* __restrict__ A,
                                               const u16* __restrict__ Bt,
                                               void* __restrict__ Cout,
                                               const float* __restrict__ bias,
                                               const float* __restrict__ res,
                                               int M, int N, int K) {
    __shared__ u16 Al[128 * 32];
    __shared__ u16 Bl[128 * 32];
    int tid = threadIdx.x;
    int lane = tid & 63, wid = tid >> 6;
    int wr = wid >> 1, wc = wid & 1;
    int lr = lane & 15, lk = lane >> 4;
    const int nbx = gridDim.x;
    const int nwg = nbx * gridDim.y;
    const int bid = blockIdx.y * nbx + blockIdx.x;
    const int swz = (bid & 7) * (nwg >> 3) + (bid >> 3);
    int m0 = (swz / nbx) * 128, n0 = (swz % nbx) * 128;

    f32x4 acc[4][4];
#pragma unroll
    for (int i = 0; i < 4; ++i)
#pragma unroll
        for (int j = 0; j < 4; ++j) acc[i][j] = (f32x4){0.f, 0.f, 0.f, 0.f};

    for (int k0 = 0; k0 < K; k0 += 32) {
        __syncthreads();
#pragma unroll
        for (int i = 0; i < 2; ++i) {
            int cb = (wid * 2 + i) * 64;
            int c = cb + lane;
            int r = c >> 2, kc = c & 3;
            gload_lds16(A + (size_t)(m0 + r) * K + k0 + kc * 8, Al + cb * 8);
            gload_lds16(Bt + (size_t)(n0 + r) * K + k0 + kc * 8, Bl + cb * 8);
        }
        __syncthreads();
        s16x8 af[4], bfr[4];
#pragma unroll
        for (int mi = 0; mi < 4; ++mi)
            af[mi] = *(const s16x8*)(Al + (wr * 64 + mi * 16 + lr) * 32 + lk * 8);
#pragma unroll
        for (int ni = 0; ni < 4; ++ni)
            bfr[ni] = *(const s16x8*)(Bl + (wc * 64 + ni * 16 + lr) * 32 + lk * 8);
#pragma unroll
        for (int mi = 0; mi < 4; ++mi)
#pragma unroll
            for (int ni = 0; ni < 4; ++ni)
                acc[mi][ni] = __builtin_amdgcn_mfma_f32_16x16x32_bf16(
                    af[mi], bfr[ni], acc[mi][ni], 0, 0, 0);
    }

#pragma unroll
    for (int mi = 0; mi < 4; ++mi) {
#pragma unroll
        for (int ni = 0; ni < 4; ++ni) {
            int col = n0 + wc * 64 + ni * 16 + lr;
#pragma unroll
            for (int r = 0; r < 4; ++r) {
                int row = m0 + wr * 64 + mi * 16 + lk * 4 + r;
                float v = acc[mi][ni][r];
                size_t idx = (size_t)row * N + col;
                if constexpr (EPI == 1) {
                    ((float*)Cout)[idx] = res[idx] + v;
                } else {
                    ((float*)Cout)[idx] = res[idx] + v + bias[col];
                }
            }
        }
    }
}

// ---------------- causal flash attention (R1 structure, validated) ----------------
__global__ __launch_bounds__(256) void attn_k(const u16* __restrict__ qkv,
                                              const u16* __restrict__ vT,
                                              u16* __restrict__ y) {
    int pidx = blockIdx.x;
    int bh = blockIdx.y;
    int b = bh >> 4, h = bh & 15;
    int tid = threadIdx.x, lane = tid & 63, wid = tid >> 6;
    int lr = lane & 15, lk = lane >> 4;

    __shared__ u16 Kl[2][8192];
    __shared__ u16 Vl[2][8192];

    const u16* qkp = qkv + (size_t)(b * TSEQ) * 3072 + h * HDIM;
    const u16* kkp = qkp + CDIM;
    const u16* vtp = vT + (size_t)bh * HDIM * TSEQ;

    auto STAGE = [&](int buf, int kv0) {
#pragma unroll
        for (int c = 0; c < 4; ++c) {
            int s = c * 256 + wid * 64 + lane;
            int kr = s >> 3, kc = s & 7;
            int gkc = kc ^ (kr & 7);
            gload_lds16(kkp + (size_t)(kv0 + kr) * 3072 + gkc * 8,
                        &Kl[buf][(size_t)(c * 256 + wid * 64) * 8]);
            int vd = s >> 4, vc = s & 15;
            int gvc = (vc & 8) | ((vc ^ vd) & 7);
            gload_lds16(vtp + (size_t)vd * TSEQ + kv0 + gvc * 8,
                        &Vl[buf][(size_t)(c * 256 + wid * 64) * 8]);
        }
    };

    auto qtile = [&](int qt) {
        int qbase = qt * 128 + wid * 32;
        int qend = qbase + 31;
        s16x8 qf[2][2];
#pragma unroll
        for (int qs = 0; qs < 2; ++qs)
#pragma unroll
            for (int db = 0; db < 2; ++db)
                qf[qs][db] = *(const s16x8*)(qkp +
                    (size_t)(qbase + qs * 16 + lr) * 3072 + db * 32 + lk * 8);
        f32x4 acc[2][4];
#pragma unroll
        for (int qs = 0; qs < 2; ++qs)
#pragma unroll
            for (int ds = 0; ds < 4; ++ds) acc[qs][ds] = (f32x4){0.f, 0.f, 0.f, 0.f};
        float mrun[2] = {-1e30f, -1e30f};
        float lrun[2] = {0.f, 0.f};

        int nt = qt + 1;
        STAGE(0, 0);
        for (int t = 0; t < nt; ++t) {
            int cur = t & 1;
            int kv0 = t * 128;
            if (t + 1 < nt) {
                STAGE(cur ^ 1, (t + 1) * 128);
                asm volatile("s_waitcnt vmcnt(8)" ::: "memory");
            } else {
                asm volatile("s_waitcnt vmcnt(0)" ::: "memory");
            }
            __builtin_amdgcn_s_barrier();
            FENCE();

            const u16* Kb = &Kl[cur][0];
            const u16* Vb = &Vl[cur][0];

            f32x4 st[8][2];
#pragma unroll
            for (int ks = 0; ks < 8; ++ks)
#pragma unroll
                for (int qs = 0; qs < 2; ++qs)
                    st[ks][qs] = (f32x4){-1e30f, -1e30f, -1e30f, -1e30f};
            __builtin_amdgcn_s_setprio(1);
#pragma unroll
            for (int ks = 0; ks < 8; ++ks) {
                if (kv0 + ks * 16 <= qend) {
                    s16x8 kf0 = *(const s16x8*)(Kb + (ks * 16 + lr) * 64 + ((lk ^ (lr & 7)) * 8));
                    s16x8 kf1 = *(const s16x8*)(Kb + (ks * 16 + lr) * 64 + (((4 + lk) ^ (lr & 7)) * 8));
#pragma unroll
                    for (int qs = 0; qs < 2; ++qs) {
                        f32x4 z = (f32x4){0.f, 0.f, 0.f, 0.f};
                        z = __builtin_amdgcn_mfma_f32_16x16x32_bf16(kf0, qf[qs][0], z, 0, 0, 0);
                        st[ks][qs] = __builtin_amdgcn_mfma_f32_16x16x32_bf16(kf1, qf[qs][1], z, 0, 0, 0);
                    }
                }
            }
            __builtin_amdgcn_s_setprio(0);

            if (kv0 + 127 > qbase) {
#pragma unroll
                for (int ks = 0; ks < 8; ++ks)
#pragma unroll
                    for (int qs = 0; qs < 2; ++qs)
#pragma unroll
                        for (int r = 0; r < 4; ++r) {
                            int k = kv0 + ks * 16 + lk * 4 + r;
                            int q = qbase + qs * 16 + lr;
                            if (k > q) st[ks][qs][r] = -1e30f;
                        }
            }

            uint32_t w[2][8][2];
#pragma unroll
            for (int qs = 0; qs < 2; ++qs) {
                float pmax = -1e30f;
#pragma unroll
                for (int ks = 0; ks < 8; ++ks) {
                    float a = fmaxf(fmaxf(st[ks][qs][0], st[ks][qs][1]),
                                    fmaxf(st[ks][qs][2], st[ks][qs][3]));
                    pmax = fmaxf(pmax, a);
                }
                pmax = fmaxf(pmax, __shfl_xor(pmax, 16));
                pmax = fmaxf(pmax, __shfl_xor(pmax, 32));
                float mnew = fmaxf(mrun[qs], pmax);
                float scale = __expf((mrun[qs] - mnew) * 0.125f);
                mrun[qs] = mnew;
                float psum = 0.f;
#pragma unroll
                for (int ks = 0; ks < 8; ++ks) {
#pragma unroll
                    for (int r = 0; r < 4; ++r) {
                        float pv = __expf((st[ks][qs][r] - mnew) * 0.125f);
                        st[ks][qs][r] = pv;
                        psum += pv;
                    }
                    w[qs][ks][0] = cvtpk(st[ks][qs][0], st[ks][qs][1]);
                    w[qs][ks][1] = cvtpk(st[ks][qs][2], st[ks][qs][3]);
                }
                psum += __shfl_xor(psum, 16);
                psum += __shfl_xor(psum, 32);
                lrun[qs] = lrun[qs] * scale + psum;
#pragma unroll
                for (int ds = 0; ds < 4; ++ds)
#pragma unroll
                    for (int r = 0; r < 4; ++r) acc[qs][ds][r] *= scale;
            }

            int A = lr + ((lane & 16) ? 32 : 0);
            bool hi = (lane & 32) != 0;
#pragma unroll
            for (int kh = 0; kh < 4; ++kh) {
                if (kv0 + kh * 32 <= qend) {
                    s16x8 vtf[4];
#pragma unroll
                    for (int ds = 0; ds < 4; ++ds) {
                        int ch = kh * 4 + lk;
                        int chs = (ch & 8) | ((ch ^ (lr & 7)) & 7);
                        vtf[ds] = *(const s16x8*)(Vb + (ds * 16 + lr) * 128 + chs * 8);
                    }
                    __builtin_amdgcn_s_setprio(1);
#pragma unroll
                    for (int qs = 0; qs < 2; ++qs) {
                        uint32_t p00 = (uint32_t)__shfl((int)w[qs][2 * kh][0], A);
                        uint32_t p01 = (uint32_t)__shfl((int)w[qs][2 * kh][1], A);
                        uint32_t p10 = (uint32_t)__shfl((int)w[qs][2 * kh + 1][0], A);
                        uint32_t p11 = (uint32_t)__shfl((int)w[qs][2 * kh + 1][1], A);
                        uint32_t q00 = (uint32_t)__shfl((int)w[qs][2 * kh][0], A + 16);
                        uint32_t q01 = (uint32_t)__shfl((int)w[qs][2 * kh][1], A + 16);
                        uint32_t q10 = (uint32_t)__shfl((int)w[qs][2 * kh + 1][0], A + 16);
                        uint32_t q11 = (uint32_t)__shfl((int)w[qs][2 * kh + 1][1], A + 16);
                        union { uint32_t u[4]; s16x8 v; } pf;
                        pf.u[0] = hi ? p10 : p00;
                        pf.u[1] = hi ? p11 : p01;
                        pf.u[2] = hi ? q10 : q00;
                        pf.u[3] = hi ? q11 : q01;
#pragma unroll
                        for (int ds = 0; ds < 4; ++ds)
                            acc[qs][ds] = __builtin_amdgcn_mfma_f32_16x16x32_bf16(
                                vtf[ds], pf.v, acc[qs][ds], 0, 0, 0);
                    }
                    __builtin_amdgcn_s_setprio(0);
                }
            }
            FENCE();
            __builtin_amdgcn_s_barrier();
            FENCE();
        }

        float rl[2] = {1.f / lrun[0], 1.f / lrun[1]};
#pragma unroll
        for (int qs = 0; qs < 2; ++qs) {
            int q = qbase + qs * 16 + lr;
            u16* yr = y + (size_t)(b * TSEQ + q) * CDIM + h * HDIM;
#pragma unroll
            for (int ds = 0; ds < 4; ++ds)
#pragma unroll
                for (int r = 0; r < 4; ++r)
                    yr[ds * 16 + lk * 4 + r] = f2bu(acc[qs][ds][r] * rl[qs]);
        }
    };

    qtile(pidx);
    qtile(15 - pidx);
}

extern "C" void kernel_launch(void* const* d_in, const int* in_sizes, int n_in,
                              void* d_out, int out_size, void* d_ws, size_t ws_size,
                              hipStream_t stream) {
    (void)in_sizes; (void)n_in; (void)out_size; (void)ws_size;
    const float* x      = (const float*)d_in[0];
    const float* ln1_w  = (const float*)d_in[1];
    const float* w_attn = (const float*)d_in[2];
    const float* w_proj = (const float*)d_in[3];
    const float* ln2_w  = (const float*)d_in[4];
    const float* w_fc1  = (const float*)d_in[5];
    const float* b_fc1  = (const float*)d_in[6];
    const float* w_fc2  = (const float*)d_in[7];
    const float* b_fc2  = (const float*)d_in[8];
    float* out = (float*)d_out;
    char* ws = (char*)d_ws;

    u16*   wT_attn = (u16*)(ws + 0);            // [3072][1024] bf16, 6 MB
    u16*   wT_proj = (u16*)(ws + 6291456);      // [1024][1024], 2 MB
    u16*   wT_fc1  = (u16*)(ws + 8388608);      // [4096][1024], 8 MB
    u16*   wT_fc2  = (u16*)(ws + 16777216);     // [1024][4096], 8 MB
    u16*   h       = (u16*)(ws + 25165824);     // [8192][1024]
    u16*   qkvb    = (u16*)(ws + 41943040);     // [8192][3072]
    u16*   yb      = (u16*)(ws + 92274688);     // [8192][1024]
    float* x1      = (float*)(ws + 109051904);  // [8192][1024] f32
    u16*   vTb     = (u16*)(ws + 109051904);    // [64][64][2048] bf16 (aliases x1;
                                                // vT dead before proj writes x1)
    u16*   h3      = (u16*)(ws + 41943040);     // [8192][4096] reuses qkv region

    twb_k<<<dim3(3072 / 32, 1024 / 32), 256, 0, stream>>>(w_attn, wT_attn, 1024, 3072);
    twb_k<<<dim3(1024 / 32, 1024 / 32), 256, 0, stream>>>(w_proj, wT_proj, 1024, 1024);
    twb_k<<<dim3(4096 / 32, 1024 / 32), 256, 0, stream>>>(w_fc1, wT_fc1, 1024, 4096);
    twb_k<<<dim3(1024 / 32, 4096 / 32), 256, 0, stream>>>(w_fc2, wT_fc2, 4096, 1024);

    ln_k<<<8192, 256, 0, stream>>>(x, ln1_w, h);
    gemm8p<0><<<dim3(3072 / 256, 8192 / 256), 512, 0, stream>>>(h, wT_attn, qkvb, vTb, nullptr, 8192, 3072, 1024);
    attn_k<<<dim3(8, NBATCH * NHEAD), 256, 0, stream>>>(qkvb, vTb, yb);
    gemm_bt<1><<<dim3(1024 / 128, 8192 / 128), 256, 0, stream>>>(yb, wT_proj, x1, nullptr, x, 8192, 1024, 1024);
    ln_k<<<8192, 256, 0, stream>>>(x1, ln2_w, h);
    gemm8p<2><<<dim3(4096 / 256, 8192 / 256), 512, 0, stream>>>(h, wT_fc1, h3, nullptr, b_fc1, 8192, 4096, 1024);
    gemm_bt<3><<<dim3(1024 / 128, 8192 / 128), 256, 0, stream>>>(h3, wT_fc2, out, b_fc2, x1, 8192, 1024, 4096);
}

// Round 7
// 591.120 us; speedup vs baseline: 1.4670x; 1.0395x over previous
//
#include <hip/hip_runtime.h>
#include <cstdint>

// Transformer block, bf16 MFMA implementation.
// R6: attn PV rewritten — P routed through per-wave chunk-swizzled LDS
// (ds_write_b64/ds_read_b128) replacing the 64-bpermute shuffle storm.
// LDS = 80 KiB exactly (2 blocks/CU). Everything else identical to R5.

#define CDIM 1024
#define TSEQ 2048
#define NBATCH 4
#define NHEAD 16
#define HDIM 64
#define FDIM 4096

typedef unsigned short u16;
typedef __attribute__((ext_vector_type(8))) short s16x8;   // 8 bf16 in 4 VGPRs
typedef __attribute__((ext_vector_type(4))) float f32x4;

__device__ __forceinline__ u16 f2bu(float f) {             // f32 -> bf16 bits, RNE
    uint32_t u = __builtin_bit_cast(uint32_t, f);
    uint32_t r = (u + 0x7FFFu + ((u >> 16) & 1u)) >> 16;
    return (u16)r;
}

__device__ __forceinline__ uint32_t cvtpk(float lo, float hi) {  // packed bf16
    uint32_t r;
    asm("v_cvt_pk_bf16_f32 %0, %1, %2" : "=v"(r) : "v"(lo), "v"(hi));
    return r;
}

typedef __attribute__((address_space(3))) unsigned int lds_u32;
typedef __attribute__((address_space(1))) const unsigned int glb_u32;
__device__ __forceinline__ void gload_lds16(const void* g, void* l) {
    // async global->LDS, 16B per lane; LDS dest = uniform base + lane*16
    __builtin_amdgcn_global_load_lds((glb_u32*)g, (lds_u32*)l, 16, 0, 0);
}

#define FENCE() asm volatile("" ::: "memory")

// ---------------- weight fp32 [K][N] -> bf16 transposed [N][K] ----------------
__global__ __launch_bounds__(256) void twb_k(const float* __restrict__ in,
                                             u16* __restrict__ out, int K, int N) {
    __shared__ float tile[32][33];
    int n0 = blockIdx.x * 32, k0 = blockIdx.y * 32;
    int tx = threadIdx.x & 31, ty = threadIdx.x >> 5;
#pragma unroll
    for (int i = 0; i < 32; i += 8)
        tile[ty + i][tx] = in[(size_t)(k0 + ty + i) * N + n0 + tx];
    __syncthreads();
#pragma unroll
    for (int i = 0; i < 32; i += 8)
        out[(size_t)(n0 + ty + i) * K + k0 + tx] = f2bu(tile[tx][ty + i]);
}

// ---------------- layernorm (f32 in, bf16 out), one row per block ----------------
__global__ __launch_bounds__(256) void ln_k(const float* __restrict__ x,
                                            const float* __restrict__ w,
                                            u16* __restrict__ out) {
    int row = blockIdx.x;
    int t = threadIdx.x;
    const float4* xr = (const float4*)(x + (size_t)row * CDIM);
    float4 v = xr[t];
    float s = v.x + v.y + v.z + v.w;
    float sq = v.x * v.x + v.y * v.y + v.z * v.z + v.w * v.w;
#pragma unroll
    for (int o = 32; o > 0; o >>= 1) { s += __shfl_xor(s, o); sq += __shfl_xor(sq, o); }
    __shared__ float ps[4], pq[4];
    int wid = t >> 6, lane = t & 63;
    if (lane == 0) { ps[wid] = s; pq[wid] = sq; }
    __syncthreads();
    s = ps[0] + ps[1] + ps[2] + ps[3];
    sq = pq[0] + pq[1] + pq[2] + pq[3];
    float mu = s * (1.0f / CDIM);
    float var = sq * (1.0f / CDIM) - mu * mu;
    float rstd = rsqrtf(var + 1e-5f);
    float4 wv = ((const float4*)w)[t];
    union { u16 h[4]; uint2 u; } pk;
    pk.h[0] = f2bu((v.x - mu) * rstd * wv.x);
    pk.h[1] = f2bu((v.y - mu) * rstd * wv.y);
    pk.h[2] = f2bu((v.z - mu) * rstd * wv.z);
    pk.h[3] = f2bu((v.w - mu) * rstd * wv.w);
    ((uint2*)(out + (size_t)row * CDIM))[t] = pk.u;
}

// ================= 256^2 8-phase GEMM (QKV: EPI0, FC1: EPI2) =================
// C[M,N] = A[M,K] * Bt[N,K]^T, bf16 in, fp32 acc. NT = K/64 must be EVEN.
// EPI 0: cols<2048 -> bf16 C; cols>=2048 (V) -> vT[bh][d][t]
// EPI 2: +bias, relu -> bf16
template <int EPI>
__global__ __launch_bounds__(512, 2) void gemm8p(const u16* __restrict__ A,
                                                 const u16* __restrict__ Bt,
                                                 void* __restrict__ Cout,
                                                 u16* __restrict__ Vout,
                                                 const float* __restrict__ bias,
                                                 int M, int N, int K) {
    // [slot][op(A=0,B=1)][khalf][r2][8 slots x 8 u16]; 16KB per (slot,op,kh) = 128KB
    __shared__ __align__(16) u16 L[2][2][2][128][64];
    const int tid = threadIdx.x, lane = tid & 63, wid = tid >> 6;
    const int lr = lane & 15, lk = lane >> 4;
    const int wr = wid >> 2, wcn = wid & 3;
    // T1 XCD swizzle (nwg % 8 == 0 for all our launches)
    const int nbx = gridDim.x;
    const int nwg = nbx * gridDim.y;
    const int bid = blockIdx.y * nbx + blockIdx.x;
    const int swz = (bid & 7) * (nwg >> 3) + (bid >> 3);
    const int m0 = (swz / nbx) * 256, n0 = (swz % nbx) * 256;
    const int NT = K >> 6;

    auto STG = [&](int kt, int part, int kh) {
        const u16* src = part ? Bt : A;
        const int base0 = part ? n0 : m0;
        u16* dst = &L[kt & 1][part][kh][0][0];
#pragma unroll
        for (int i = 0; i < 2; ++i) {
            int t = i * 512 + tid;
            int r2 = t >> 3, se = t & 7;
            int s = se ^ (r2 & 7);                 // inverse swizzle on global src
            int row = 2 * r2 + (s >> 2), c = s & 3;
            gload_lds16(src + (size_t)(base0 + row) * K + kt * 64 + kh * 32 + c * 8,
                        dst + (size_t)(i * 512 + wid * 64) * 8);
        }
    };

    f32x4 acc[8][4];
#pragma unroll
    for (int i = 0; i < 8; ++i)
#pragma unroll
        for (int j = 0; j < 4; ++j) acc[i][j] = (f32x4){0.f, 0.f, 0.f, 0.f};

    // prologue: tile0 complete + tile1 k0 halves = 12 loads/wave; retire tile0-k0.
    STG(0, 0, 0); STG(0, 1, 0); STG(0, 0, 1); STG(0, 1, 1);
    STG(1, 0, 0); STG(1, 1, 0);
    asm volatile("s_waitcnt vmcnt(8)" ::: "memory");
    FENCE(); __builtin_amdgcn_s_barrier(); FENCE();

    const int se = (((lr & 1) << 2) | lk) ^ (lr >> 1);   // swizzled read slot
    const int rA0 = wr * 64 + (lr >> 1);                  // A r2 base (this wave)
    const int rB0 = wcn * 32 + (lr >> 1);                 // B r2 base

    s16x8 af[4], bf[4];

#define LDA(kh, ch) \
    { _Pragma("unroll") for (int q = 0; q < 4; ++q) \
        af[q] = *(const s16x8*)&L[slot][0][kh][rA0 + (ch) * 32 + q * 8][se * 8]; }
#define LDB(kh) \
    { _Pragma("unroll") for (int q = 0; q < 4; ++q) \
        bf[q] = *(const s16x8*)&L[slot][1][kh][rB0 + q * 8][se * 8]; }
#define MM(ch) \
    { __builtin_amdgcn_s_setprio(1); \
      _Pragma("unroll") for (int qm = 0; qm < 4; ++qm) \
      _Pragma("unroll") for (int ni = 0; ni < 4; ++ni) \
        acc[(ch) * 4 + qm][ni] = __builtin_amdgcn_mfma_f32_16x16x32_bf16( \
            af[qm], bf[ni], acc[(ch) * 4 + qm][ni], 0, 0, 0); \
      __builtin_amdgcn_s_setprio(0); }
#define BAR() { FENCE(); __builtin_amdgcn_s_barrier(); FENCE(); }
#define CKPT() asm volatile("s_waitcnt vmcnt(8)" ::: "memory")

    for (int j = 0; j < NT; ++j) {
        const int slot = j & 1;
        // wrapped stage targets: tail re-stages tile 0/1 (never read) so the
        // vmcnt(8) ledger stays in steady state — avoids tail race. NT even.
        const int jn1 = (j + 1 < NT) ? j + 1 : j + 1 - NT;
        const int jn2 = (j + 2 < NT) ? j + 2 : j + 2 - NT;
        // P1: C-half0 x k0
        LDA(0, 0); LDB(0);
        STG(jn1, 0, 1);
        BAR(); MM(0); BAR();
        // P2: C-half1 x k0
        LDA(0, 1);
        STG(jn1, 1, 1);
        CKPT();
        BAR(); MM(1); BAR();
        // P3: C-half0 x k1
        LDA(1, 0); LDB(1);
        STG(jn2, 0, 0);
        BAR(); MM(0); BAR();
        // P4: C-half1 x k1
        LDA(1, 1);
        STG(jn2, 1, 0);
        CKPT();
        BAR(); MM(1); BAR();
    }
#undef LDA
#undef LDB
#undef MM
#undef BAR
#undef CKPT

#pragma unroll
    for (int mi = 0; mi < 8; ++mi) {
#pragma unroll
        for (int ni = 0; ni < 4; ++ni) {
            int col = n0 + wcn * 64 + ni * 16 + lr;
#pragma unroll
            for (int r = 0; r < 4; ++r) {
                int row = m0 + wr * 128 + mi * 16 + lk * 4 + r;
                float v = acc[mi][ni][r];
                size_t idx = (size_t)row * N + col;
                if constexpr (EPI == 0) {
                    if (col < 2048) {
                        ((u16*)Cout)[idx] = f2bu(v);
                    } else {
                        int bb = row >> 11, tt = row & 2047, cc = col - 2048;
                        Vout[((size_t)(bb * 16 + (cc >> 6)) * 64 + (cc & 63)) * 2048 + tt] = f2bu(v);
                    }
                } else {
                    ((u16*)Cout)[idx] = f2bu(fmaxf(v + bias[col], 0.f));
                }
            }
        }
    }
}

// ---------------- 128^2 GEMM (proj: EPI1, fc2: EPI3) ----------------
// EPI 1: +res(f32) -> f32     3: +bias +res(f32) -> f32
template <int EPI>
__global__ __launch_bounds__(256) void gemm_bt(const u16* __restrict__ A,
                                               const u16* __restrict__ Bt,
                                               void* __restrict__ Cout,
                                               const float* __restrict__ bias,
                                               const float* __restrict__ res,
                                               int M, int N, int K) {
    __shared__ u16 Al[128 * 32];
    __shared__ u16 Bl[128 * 32];
    int tid = threadIdx.x;
    int lane = tid & 63, wid = tid >> 6;
    int wr = wid >> 1, wc = wid & 1;
    int lr = lane & 15, lk = lane >> 4;
    const int nbx = gridDim.x;
    const int nwg = nbx * gridDim.y;
    const int bid = blockIdx.y * nbx + blockIdx.x;
    const int swz = (bid & 7) * (nwg >> 3) + (bid >> 3);
    int m0 = (swz / nbx) * 128, n0 = (swz % nbx) * 128;

    f32x4 acc[4][4];
#pragma unroll
    for (int i = 0; i < 4; ++i)
#pragma unroll
        for (int j = 0; j < 4; ++j) acc[i][j] = (f32x4){0.f, 0.f, 0.f, 0.f};

    for (int k0 = 0; k0 < K; k0 += 32) {
        __syncthreads();
#pragma unroll
        for (int i = 0; i < 2; ++i) {
            int cb = (wid * 2 + i) * 64;
            int c = cb + lane;
            int r = c >> 2, kc = c & 3;
            gload_lds16(A + (size_t)(m0 + r) * K + k0 + kc * 8, Al + cb * 8);
            gload_lds16(Bt + (size_t)(n0 + r) * K + k0 + kc * 8, Bl + cb * 8);
        }
        __syncthreads();
        s16x8 af[4], bfr[4];
#pragma unroll
        for (int mi = 0; mi < 4; ++mi)
            af[mi] = *(const s16x8*)(Al + (wr * 64 + mi * 16 + lr) * 32 + lk * 8);
#pragma unroll
        for (int ni = 0; ni < 4; ++ni)
            bfr[ni] = *(const s16x8*)(Bl + (wc * 64 + ni * 16 + lr) * 32 + lk * 8);
#pragma unroll
        for (int mi = 0; mi < 4; ++mi)
#pragma unroll
            for (int ni = 0; ni < 4; ++ni)
                acc[mi][ni] = __builtin_amdgcn_mfma_f32_16x16x32_bf16(
                    af[mi], bfr[ni], acc[mi][ni], 0, 0, 0);
    }

#pragma unroll
    for (int mi = 0; mi < 4; ++mi) {
#pragma unroll
        for (int ni = 0; ni < 4; ++ni) {
            int col = n0 + wc * 64 + ni * 16 + lr;
#pragma unroll
            for (int r = 0; r < 4; ++r) {
                int row = m0 + wr * 64 + mi * 16 + lk * 4 + r;
                float v = acc[mi][ni][r];
                size_t idx = (size_t)row * N + col;
                if constexpr (EPI == 1) {
                    ((float*)Cout)[idx] = res[idx] + v;
                } else {
                    ((float*)Cout)[idx] = res[idx] + v + bias[col];
                }
            }
        }
    }
}

// ---------------- causal flash attention (R6: P via swizzled LDS) ----------------
__global__ __launch_bounds__(256) void attn_k(const u16* __restrict__ qkv,
                                              const u16* __restrict__ vT,
                                              u16* __restrict__ y) {
    int pidx = blockIdx.x;
    int bh = blockIdx.y;
    int b = bh >> 4, h = bh & 15;
    int tid = threadIdx.x, lane = tid & 63, wid = tid >> 6;
    int lr = lane & 15, lk = lane >> 4;

    __shared__ u16 Kl[2][8192];                  // 32 KB
    __shared__ u16 Vl[2][8192];                  // 32 KB
    __shared__ __align__(16) u16 Pl[4][2048];    // 16 KB: per-wave P half-tile
                                                 // [32 q][64 k], chunk-swizzled

    const u16* qkp = qkv + (size_t)(b * TSEQ) * 3072 + h * HDIM;
    const u16* kkp = qkp + CDIM;
    const u16* vtp = vT + (size_t)bh * HDIM * TSEQ;

    auto STAGE = [&](int buf, int kv0) {
#pragma unroll
        for (int c = 0; c < 4; ++c) {
            int s = c * 256 + wid * 64 + lane;
            int kr = s >> 3, kc = s & 7;
            int gkc = kc ^ (kr & 7);
            gload_lds16(kkp + (size_t)(kv0 + kr) * 3072 + gkc * 8,
                        &Kl[buf][(size_t)(c * 256 + wid * 64) * 8]);
            int vd = s >> 4, vc = s & 15;
            int gvc = (vc & 8) | ((vc ^ vd) & 7);
            gload_lds16(vtp + (size_t)vd * TSEQ + kv0 + gvc * 8,
                        &Vl[buf][(size_t)(c * 256 + wid * 64) * 8]);
        }
    };

    auto qtile = [&](int qt) {
        int qbase = qt * 128 + wid * 32;
        int qend = qbase + 31;
        s16x8 qf[2][2];
#pragma unroll
        for (int qs = 0; qs < 2; ++qs)
#pragma unroll
            for (int db = 0; db < 2; ++db)
                qf[qs][db] = *(const s16x8*)(qkp +
                    (size_t)(qbase + qs * 16 + lr) * 3072 + db * 32 + lk * 8);
        f32x4 acc[2][4];
#pragma unroll
        for (int qs = 0; qs < 2; ++qs)
#pragma unroll
            for (int ds = 0; ds < 4; ++ds) acc[qs][ds] = (f32x4){0.f, 0.f, 0.f, 0.f};
        float mrun[2] = {-1e30f, -1e30f};
        float lrun[2] = {0.f, 0.f};

        int nt = qt + 1;
        STAGE(0, 0);
        for (int t = 0; t < nt; ++t) {
            int cur = t & 1;
            int kv0 = t * 128;
            if (t + 1 < nt) {
                STAGE(cur ^ 1, (t + 1) * 128);
                asm volatile("s_waitcnt vmcnt(8)" ::: "memory");
            } else {
                asm volatile("s_waitcnt vmcnt(0)" ::: "memory");
            }
            __builtin_amdgcn_s_barrier();
            FENCE();

            const u16* Kb = &Kl[cur][0];
            const u16* Vb = &Vl[cur][0];

            // ---- S^T = K·Q^T (row=k, col=q) ----
            f32x4 st[8][2];
#pragma unroll
            for (int ks = 0; ks < 8; ++ks)
#pragma unroll
                for (int qs = 0; qs < 2; ++qs)
                    st[ks][qs] = (f32x4){-1e30f, -1e30f, -1e30f, -1e30f};
            __builtin_amdgcn_s_setprio(1);
#pragma unroll
            for (int ks = 0; ks < 8; ++ks) {
                if (kv0 + ks * 16 <= qend) {
                    s16x8 kf0 = *(const s16x8*)(Kb + (ks * 16 + lr) * 64 + ((lk ^ (lr & 7)) * 8));
                    s16x8 kf1 = *(const s16x8*)(Kb + (ks * 16 + lr) * 64 + (((4 + lk) ^ (lr & 7)) * 8));
#pragma unroll
                    for (int qs = 0; qs < 2; ++qs) {
                        f32x4 z = (f32x4){0.f, 0.f, 0.f, 0.f};
                        z = __builtin_amdgcn_mfma_f32_16x16x32_bf16(kf0, qf[qs][0], z, 0, 0, 0);
                        st[ks][qs] = __builtin_amdgcn_mfma_f32_16x16x32_bf16(kf1, qf[qs][1], z, 0, 0, 0);
                    }
                }
            }
            __builtin_amdgcn_s_setprio(0);

            if (kv0 + 127 > qbase) {   // diagonal tiles: per-element causal mask
#pragma unroll
                for (int ks = 0; ks < 8; ++ks)
#pragma unroll
                    for (int qs = 0; qs < 2; ++qs)
#pragma unroll
                        for (int r = 0; r < 4; ++r) {
                            int k = kv0 + ks * 16 + lk * 4 + r;
                            int q = qbase + qs * 16 + lr;
                            if (k > q) st[ks][qs][r] = -1e30f;
                        }
            }

            // ---- online softmax (q = lr lane-local; scale folded into exp) ----
#pragma unroll
            for (int qs = 0; qs < 2; ++qs) {
                float pmax = -1e30f;
#pragma unroll
                for (int ks = 0; ks < 8; ++ks) {
                    float a = fmaxf(fmaxf(st[ks][qs][0], st[ks][qs][1]),
                                    fmaxf(st[ks][qs][2], st[ks][qs][3]));
                    pmax = fmaxf(pmax, a);
                }
                pmax = fmaxf(pmax, __shfl_xor(pmax, 16));
                pmax = fmaxf(pmax, __shfl_xor(pmax, 32));
                float mnew = fmaxf(mrun[qs], pmax);
                float scale = __expf((mrun[qs] - mnew) * 0.125f);
                mrun[qs] = mnew;
                float psum = 0.f;
#pragma unroll
                for (int ks = 0; ks < 8; ++ks) {
#pragma unroll
                    for (int r = 0; r < 4; ++r) {
                        float pv = __expf((st[ks][qs][r] - mnew) * 0.125f);
                        st[ks][qs][r] = pv;
                        psum += pv;
                    }
                }
                psum += __shfl_xor(psum, 16);
                psum += __shfl_xor(psum, 32);
                lrun[qs] = lrun[qs] * scale + psum;
#pragma unroll
                for (int ds = 0; ds < 4; ++ds)
#pragma unroll
                    for (int r = 0; r < 4; ++r) acc[qs][ds][r] *= scale;
            }

            // ---- PV via per-wave LDS, two k-halves of 64 ----
            // write: lane (lr,lk) holds P^T[k=ks*16+lk*4+r][q=qs*16+lr];
            //   8B at [q][ksp*32+lk*8 bytes], chunk c=2ksp+(lk>>1), c^=lr&7.
            // read: B-frag lane lr=q, 16B at [q][khp*64+lk*16 bytes],
            //   chunk c=4khp+lk, c^=lr&7. mfma(Vt-frag, P-frag) = O^T as before.
#pragma unroll
            for (int hh = 0; hh < 2; ++hh) {
                if (kv0 + hh * 64 > qend) break;   // wave-uniform
#pragma unroll
                for (int qs = 0; qs < 2; ++qs)
#pragma unroll
                    for (int ksp = 0; ksp < 4; ++ksp) {
                        int ks = hh * 4 + ksp;
                        uint32_t w0 = cvtpk(st[ks][qs][0], st[ks][qs][1]);
                        uint32_t w1 = cvtpk(st[ks][qs][2], st[ks][qs][3]);
                        int q = qs * 16 + lr;
                        int cp = (2 * ksp + (lk >> 1)) ^ (lr & 7);
                        *(uint2*)&Pl[wid][q * 64 + cp * 8 + (lk & 1) * 4] =
                            make_uint2(w0, w1);
                    }
#pragma unroll
                for (int khp = 0; khp < 2; ++khp) {
                    int kh = hh * 2 + khp;
                    if (kv0 + kh * 32 > qend) break;   // wave-uniform
                    s16x8 vtf[4];
#pragma unroll
                    for (int ds = 0; ds < 4; ++ds) {
                        int ch = kh * 4 + lk;
                        int chs = (ch & 8) | ((ch ^ (lr & 7)) & 7);
                        vtf[ds] = *(const s16x8*)(Vb + (ds * 16 + lr) * 128 + chs * 8);
                    }
                    s16x8 pa[2];
#pragma unroll
                    for (int qs = 0; qs < 2; ++qs) {
                        int q = qs * 16 + lr;
                        int cp = (4 * khp + lk) ^ (lr & 7);
                        pa[qs] = *(const s16x8*)&Pl[wid][q * 64 + cp * 8];
                    }
                    __builtin_amdgcn_s_setprio(1);
#pragma unroll
                    for (int qs = 0; qs < 2; ++qs)
#pragma unroll
                        for (int ds = 0; ds < 4; ++ds)
                            acc[qs][ds] = __builtin_amdgcn_mfma_f32_16x16x32_bf16(
                                vtf[ds], pa[qs], acc[qs][ds], 0, 0, 0);
                    __builtin_amdgcn_s_setprio(0);
                }
            }
            FENCE();
            __builtin_amdgcn_s_barrier();
            FENCE();
        }

        // ---- epilogue: acc is O^T (row=d=lk*4+r, col=q=lr) ----
        float rl[2] = {1.f / lrun[0], 1.f / lrun[1]};
#pragma unroll
        for (int qs = 0; qs < 2; ++qs) {
            int q = qbase + qs * 16 + lr;
            u16* yr = y + (size_t)(b * TSEQ + q) * CDIM + h * HDIM;
#pragma unroll
            for (int ds = 0; ds < 4; ++ds)
#pragma unroll
                for (int r = 0; r < 4; ++r)
                    yr[ds * 16 + lk * 4 + r] = f2bu(acc[qs][ds][r] * rl[qs]);
        }
    };

    qtile(pidx);
    qtile(15 - pidx);
}

extern "C" void kernel_launch(void* const* d_in, const int* in_sizes, int n_in,
                              void* d_out, int out_size, void* d_ws, size_t ws_size,
                              hipStream_t stream) {
    (void)in_sizes; (void)n_in; (void)out_size; (void)ws_size;
    const float* x      = (const float*)d_in[0];
    const float* ln1_w  = (const float*)d_in[1];
    const float* w_attn = (const float*)d_in[2];
    const float* w_proj = (const float*)d_in[3];
    const float* ln2_w  = (const float*)d_in[4];
    const float* w_fc1  = (const float*)d_in[5];
    const float* b_fc1  = (const float*)d_in[6];
    const float* w_fc2  = (const float*)d_in[7];
    const float* b_fc2  = (const float*)d_in[8];
    float* out = (float*)d_out;
    char* ws = (char*)d_ws;

    u16*   wT_attn = (u16*)(ws + 0);            // [3072][1024] bf16, 6 MB
    u16*   wT_proj = (u16*)(ws + 6291456);      // [1024][1024], 2 MB
    u16*   wT_fc1  = (u16*)(ws + 8388608);      // [4096][1024], 8 MB
    u16*   wT_fc2  = (u16*)(ws + 16777216);     // [1024][4096], 8 MB
    u16*   h       = (u16*)(ws + 25165824);     // [8192][1024]
    u16*   qkvb    = (u16*)(ws + 41943040);     // [8192][3072]
    u16*   yb      = (u16*)(ws + 92274688);     // [8192][1024]
    float* x1      = (float*)(ws + 109051904);  // [8192][1024] f32
    u16*   vTb     = (u16*)(ws + 109051904);    // [64][64][2048] bf16 (aliases x1;
                                                // vT dead before proj writes x1)
    u16*   h3      = (u16*)(ws + 41943040);     // [8192][4096] reuses qkv region

    twb_k<<<dim3(3072 / 32, 1024 / 32), 256, 0, stream>>>(w_attn, wT_attn, 1024, 3072);
    twb_k<<<dim3(1024 / 32, 1024 / 32), 256, 0, stream>>>(w_proj, wT_proj, 1024, 1024);
    twb_k<<<dim3(4096 / 32, 1024 / 32), 256, 0, stream>>>(w_fc1, wT_fc1, 1024, 4096);
    twb_k<<<dim3(1024 / 32, 4096 / 32), 256, 0, stream>>>(w_fc2, wT_fc2, 4096, 1024);

    ln_k<<<8192, 256, 0, stream>>>(x, ln1_w, h);
    gemm8p<0><<<dim3(3072 / 256, 8192 / 256), 512, 0, stream>>>(h, wT_attn, qkvb, vTb, nullptr, 8192, 3072, 1024);
    attn_k<<<dim3(8, NBATCH * NHEAD), 256, 0, stream>>>(qkvb, vTb, yb);
    gemm_bt<1><<<dim3(1024 / 128, 8192 / 128), 256, 0, stream>>>(yb, wT_proj, x1, nullptr, x, 8192, 1024, 1024);
    ln_k<<<8192, 256, 0, stream>>>(x1, ln2_w, h);
    gemm8p<2><<<dim3(4096 / 256, 8192 / 256), 512, 0, stream>>>(h, wT_fc1, h3, nullptr, b_fc1, 8192, 4096, 1024);
    gemm_bt<3><<<dim3(1024 / 128, 8192 / 128), 256, 0, stream>>>(h3, wT_fc2, out, b_fc2, x1, 8192, 1024, 4096);
}

// Round 8
// 578.193 us; speedup vs baseline: 1.4998x; 1.0224x over previous
//
#include <hip/hip_runtime.h>
#include <cstdint>

// Transformer block, bf16 MFMA implementation.
// R7: attention made barrier-free — K/V^T MFMA fragments read directly from
// global (L2-resident working set), no K/V LDS staging, no block barriers;
// waves fully independent. P stays in per-wave swizzled LDS (16 KiB total).
// GEMMs unchanged from R6.

#define CDIM 1024
#define TSEQ 2048
#define NBATCH 4
#define NHEAD 16
#define HDIM 64
#define FDIM 4096

typedef unsigned short u16;
typedef __attribute__((ext_vector_type(8))) short s16x8;   // 8 bf16 in 4 VGPRs
typedef __attribute__((ext_vector_type(4))) float f32x4;

__device__ __forceinline__ u16 f2bu(float f) {             // f32 -> bf16 bits, RNE
    uint32_t u = __builtin_bit_cast(uint32_t, f);
    uint32_t r = (u + 0x7FFFu + ((u >> 16) & 1u)) >> 16;
    return (u16)r;
}

__device__ __forceinline__ uint32_t cvtpk(float lo, float hi) {  // packed bf16
    uint32_t r;
    asm("v_cvt_pk_bf16_f32 %0, %1, %2" : "=v"(r) : "v"(lo), "v"(hi));
    return r;
}

typedef __attribute__((address_space(3))) unsigned int lds_u32;
typedef __attribute__((address_space(1))) const unsigned int glb_u32;
__device__ __forceinline__ void gload_lds16(const void* g, void* l) {
    // async global->LDS, 16B per lane; LDS dest = uniform base + lane*16
    __builtin_amdgcn_global_load_lds((glb_u32*)g, (lds_u32*)l, 16, 0, 0);
}

#define FENCE() asm volatile("" ::: "memory")

// ---------------- weight fp32 [K][N] -> bf16 transposed [N][K] ----------------
__global__ __launch_bounds__(256) void twb_k(const float* __restrict__ in,
                                             u16* __restrict__ out, int K, int N) {
    __shared__ float tile[32][33];
    int n0 = blockIdx.x * 32, k0 = blockIdx.y * 32;
    int tx = threadIdx.x & 31, ty = threadIdx.x >> 5;
#pragma unroll
    for (int i = 0; i < 32; i += 8)
        tile[ty + i][tx] = in[(size_t)(k0 + ty + i) * N + n0 + tx];
    __syncthreads();
#pragma unroll
    for (int i = 0; i < 32; i += 8)
        out[(size_t)(n0 + ty + i) * K + k0 + tx] = f2bu(tile[tx][ty + i]);
}

// ---------------- layernorm (f32 in, bf16 out), one row per block ----------------
__global__ __launch_bounds__(256) void ln_k(const float* __restrict__ x,
                                            const float* __restrict__ w,
                                            u16* __restrict__ out) {
    int row = blockIdx.x;
    int t = threadIdx.x;
    const float4* xr = (const float4*)(x + (size_t)row * CDIM);
    float4 v = xr[t];
    float s = v.x + v.y + v.z + v.w;
    float sq = v.x * v.x + v.y * v.y + v.z * v.z + v.w * v.w;
#pragma unroll
    for (int o = 32; o > 0; o >>= 1) { s += __shfl_xor(s, o); sq += __shfl_xor(sq, o); }
    __shared__ float ps[4], pq[4];
    int wid = t >> 6, lane = t & 63;
    if (lane == 0) { ps[wid] = s; pq[wid] = sq; }
    __syncthreads();
    s = ps[0] + ps[1] + ps[2] + ps[3];
    sq = pq[0] + pq[1] + pq[2] + pq[3];
    float mu = s * (1.0f / CDIM);
    float var = sq * (1.0f / CDIM) - mu * mu;
    float rstd = rsqrtf(var + 1e-5f);
    float4 wv = ((const float4*)w)[t];
    union { u16 h[4]; uint2 u; } pk;
    pk.h[0] = f2bu((v.x - mu) * rstd * wv.x);
    pk.h[1] = f2bu((v.y - mu) * rstd * wv.y);
    pk.h[2] = f2bu((v.z - mu) * rstd * wv.z);
    pk.h[3] = f2bu((v.w - mu) * rstd * wv.w);
    ((uint2*)(out + (size_t)row * CDIM))[t] = pk.u;
}

// ================= 256^2 8-phase GEMM (QKV: EPI0, FC1: EPI2) =================
// C[M,N] = A[M,K] * Bt[N,K]^T, bf16 in, fp32 acc. NT = K/64 must be EVEN.
// EPI 0: cols<2048 -> bf16 C; cols>=2048 (V) -> vT[bh][d][t]
// EPI 2: +bias, relu -> bf16
template <int EPI>
__global__ __launch_bounds__(512, 2) void gemm8p(const u16* __restrict__ A,
                                                 const u16* __restrict__ Bt,
                                                 void* __restrict__ Cout,
                                                 u16* __restrict__ Vout,
                                                 const float* __restrict__ bias,
                                                 int M, int N, int K) {
    // [slot][op(A=0,B=1)][khalf][r2][8 slots x 8 u16]; 16KB per (slot,op,kh) = 128KB
    __shared__ __align__(16) u16 L[2][2][2][128][64];
    const int tid = threadIdx.x, lane = tid & 63, wid = tid >> 6;
    const int lr = lane & 15, lk = lane >> 4;
    const int wr = wid >> 2, wcn = wid & 3;
    // T1 XCD swizzle (nwg % 8 == 0 for all our launches)
    const int nbx = gridDim.x;
    const int nwg = nbx * gridDim.y;
    const int bid = blockIdx.y * nbx + blockIdx.x;
    const int swz = (bid & 7) * (nwg >> 3) + (bid >> 3);
    const int m0 = (swz / nbx) * 256, n0 = (swz % nbx) * 256;
    const int NT = K >> 6;

    auto STG = [&](int kt, int part, int kh) {
        const u16* src = part ? Bt : A;
        const int base0 = part ? n0 : m0;
        u16* dst = &L[kt & 1][part][kh][0][0];
#pragma unroll
        for (int i = 0; i < 2; ++i) {
            int t = i * 512 + tid;
            int r2 = t >> 3, se = t & 7;
            int s = se ^ (r2 & 7);                 // inverse swizzle on global src
            int row = 2 * r2 + (s >> 2), c = s & 3;
            gload_lds16(src + (size_t)(base0 + row) * K + kt * 64 + kh * 32 + c * 8,
                        dst + (size_t)(i * 512 + wid * 64) * 8);
        }
    };

    f32x4 acc[8][4];
#pragma unroll
    for (int i = 0; i < 8; ++i)
#pragma unroll
        for (int j = 0; j < 4; ++j) acc[i][j] = (f32x4){0.f, 0.f, 0.f, 0.f};

    // prologue: tile0 complete + tile1 k0 halves = 12 loads/wave; retire tile0-k0.
    STG(0, 0, 0); STG(0, 1, 0); STG(0, 0, 1); STG(0, 1, 1);
    STG(1, 0, 0); STG(1, 1, 0);
    asm volatile("s_waitcnt vmcnt(8)" ::: "memory");
    FENCE(); __builtin_amdgcn_s_barrier(); FENCE();

    const int se = (((lr & 1) << 2) | lk) ^ (lr >> 1);   // swizzled read slot
    const int rA0 = wr * 64 + (lr >> 1);                  // A r2 base (this wave)
    const int rB0 = wcn * 32 + (lr >> 1);                 // B r2 base

    s16x8 af[4], bf[4];

#define LDA(kh, ch) \
    { _Pragma("unroll") for (int q = 0; q < 4; ++q) \
        af[q] = *(const s16x8*)&L[slot][0][kh][rA0 + (ch) * 32 + q * 8][se * 8]; }
#define LDB(kh) \
    { _Pragma("unroll") for (int q = 0; q < 4; ++q) \
        bf[q] = *(const s16x8*)&L[slot][1][kh][rB0 + q * 8][se * 8]; }
#define MM(ch) \
    { __builtin_amdgcn_s_setprio(1); \
      _Pragma("unroll") for (int qm = 0; qm < 4; ++qm) \
      _Pragma("unroll") for (int ni = 0; ni < 4; ++ni) \
        acc[(ch) * 4 + qm][ni] = __builtin_amdgcn_mfma_f32_16x16x32_bf16( \
            af[qm], bf[ni], acc[(ch) * 4 + qm][ni], 0, 0, 0); \
      __builtin_amdgcn_s_setprio(0); }
#define BAR() { FENCE(); __builtin_amdgcn_s_barrier(); FENCE(); }
#define CKPT() asm volatile("s_waitcnt vmcnt(8)" ::: "memory")

    for (int j = 0; j < NT; ++j) {
        const int slot = j & 1;
        // wrapped stage targets: tail re-stages tile 0/1 (never read) so the
        // vmcnt(8) ledger stays in steady state — avoids tail race. NT even.
        const int jn1 = (j + 1 < NT) ? j + 1 : j + 1 - NT;
        const int jn2 = (j + 2 < NT) ? j + 2 : j + 2 - NT;
        // P1: C-half0 x k0
        LDA(0, 0); LDB(0);
        STG(jn1, 0, 1);
        BAR(); MM(0); BAR();
        // P2: C-half1 x k0
        LDA(0, 1);
        STG(jn1, 1, 1);
        CKPT();
        BAR(); MM(1); BAR();
        // P3: C-half0 x k1
        LDA(1, 0); LDB(1);
        STG(jn2, 0, 0);
        BAR(); MM(0); BAR();
        // P4: C-half1 x k1
        LDA(1, 1);
        STG(jn2, 1, 0);
        CKPT();
        BAR(); MM(1); BAR();
    }
#undef LDA
#undef LDB
#undef MM
#undef BAR
#undef CKPT

#pragma unroll
    for (int mi = 0; mi < 8; ++mi) {
#pragma unroll
        for (int ni = 0; ni < 4; ++ni) {
            int col = n0 + wcn * 64 + ni * 16 + lr;
#pragma unroll
            for (int r = 0; r < 4; ++r) {
                int row = m0 + wr * 128 + mi * 16 + lk * 4 + r;
                float v = acc[mi][ni][r];
                size_t idx = (size_t)row * N + col;
                if constexpr (EPI == 0) {
                    if (col < 2048) {
                        ((u16*)Cout)[idx] = f2bu(v);
                    } else {
                        int bb = row >> 11, tt = row & 2047, cc = col - 2048;
                        Vout[((size_t)(bb * 16 + (cc >> 6)) * 64 + (cc & 63)) * 2048 + tt] = f2bu(v);
                    }
                } else {
                    ((u16*)Cout)[idx] = f2bu(fmaxf(v + bias[col], 0.f));
                }
            }
        }
    }
}

// ---------------- 128^2 GEMM (proj: EPI1, fc2: EPI3) ----------------
// EPI 1: +res(f32) -> f32     3: +bias +res(f32) -> f32
template <int EPI>
__global__ __launch_bounds__(256) void gemm_bt(const u16* __restrict__ A,
                                               const u16* __restrict__ Bt,
                                               void* __restrict__ Cout,
                                               const float* __restrict__ bias,
                                               const float* __restrict__ res,
                                               int M, int N, int K) {
    __shared__ u16 Al[128 * 32];
    __shared__ u16 Bl[128 * 32];
    int tid = threadIdx.x;
    int lane = tid & 63, wid = tid >> 6;
    int wr = wid >> 1, wc = wid & 1;
    int lr = lane & 15, lk = lane >> 4;
    const int nbx = gridDim.x;
    const int nwg = nbx * gridDim.y;
    const int bid = blockIdx.y * nbx + blockIdx.x;
    const int swz = (bid & 7) * (nwg >> 3) + (bid >> 3);
    int m0 = (swz / nbx) * 128, n0 = (swz % nbx) * 128;

    f32x4 acc[4][4];
#pragma unroll
    for (int i = 0; i < 4; ++i)
#pragma unroll
        for (int j = 0; j < 4; ++j) acc[i][j] = (f32x4){0.f, 0.f, 0.f, 0.f};

    for (int k0 = 0; k0 < K; k0 += 32) {
        __syncthreads();
#pragma unroll
        for (int i = 0; i < 2; ++i) {
            int cb = (wid * 2 + i) * 64;
            int c = cb + lane;
            int r = c >> 2, kc = c & 3;
            gload_lds16(A + (size_t)(m0 + r) * K + k0 + kc * 8, Al + cb * 8);
            gload_lds16(Bt + (size_t)(n0 + r) * K + k0 + kc * 8, Bl + cb * 8);
        }
        __syncthreads();
        s16x8 af[4], bfr[4];
#pragma unroll
        for (int mi = 0; mi < 4; ++mi)
            af[mi] = *(const s16x8*)(Al + (wr * 64 + mi * 16 + lr) * 32 + lk * 8);
#pragma unroll
        for (int ni = 0; ni < 4; ++ni)
            bfr[ni] = *(const s16x8*)(Bl + (wc * 64 + ni * 16 + lr) * 32 + lk * 8);
#pragma unroll
        for (int mi = 0; mi < 4; ++mi)
#pragma unroll
            for (int ni = 0; ni < 4; ++ni)
                acc[mi][ni] = __builtin_amdgcn_mfma_f32_16x16x32_bf16(
                    af[mi], bfr[ni], acc[mi][ni], 0, 0, 0);
    }

#pragma unroll
    for (int mi = 0; mi < 4; ++mi) {
#pragma unroll
        for (int ni = 0; ni < 4; ++ni) {
            int col = n0 + wc * 64 + ni * 16 + lr;
#pragma unroll
            for (int r = 0; r < 4; ++r) {
                int row = m0 + wr * 64 + mi * 16 + lk * 4 + r;
                float v = acc[mi][ni][r];
                size_t idx = (size_t)row * N + col;
                if constexpr (EPI == 1) {
                    ((float*)Cout)[idx] = res[idx] + v;
                } else {
                    ((float*)Cout)[idx] = res[idx] + v + bias[col];
                }
            }
        }
    }
}

// -------- causal flash attention (R7: barrier-free, K/V direct from L2) --------
// grid (8, B*H): block p handles q-tiles p and 15-p (uniform 17 kv-tiles).
// 4 independent waves/block, wave owns 32 q rows. No block barriers; K/V^T
// fragments loaded straight from global; P via per-wave swizzled LDS.
__global__ __launch_bounds__(256) void attn_k(const u16* __restrict__ qkv,
                                              const u16* __restrict__ vT,
                                              u16* __restrict__ y) {
    int pidx = blockIdx.x;
    int bh = blockIdx.y;
    int b = bh >> 4, h = bh & 15;
    int tid = threadIdx.x, lane = tid & 63, wid = tid >> 6;
    int lr = lane & 15, lk = lane >> 4;

    __shared__ __align__(16) u16 Pl[4][2048];    // 16 KB: per-wave P half-tile
                                                 // [32 q][64 k], chunk-swizzled

    const u16* qkp = qkv + (size_t)(b * TSEQ) * 3072 + h * HDIM;
    const u16* kkp = qkp + CDIM;
    const u16* vtp = vT + (size_t)bh * HDIM * TSEQ;

    auto qtile = [&](int qt) {
        int qbase = qt * 128 + wid * 32;
        int qend = qbase + 31;
        s16x8 qf[2][2];
#pragma unroll
        for (int qs = 0; qs < 2; ++qs)
#pragma unroll
            for (int db = 0; db < 2; ++db)
                qf[qs][db] = *(const s16x8*)(qkp +
                    (size_t)(qbase + qs * 16 + lr) * 3072 + db * 32 + lk * 8);
        f32x4 acc[2][4];
#pragma unroll
        for (int qs = 0; qs < 2; ++qs)
#pragma unroll
            for (int ds = 0; ds < 4; ++ds) acc[qs][ds] = (f32x4){0.f, 0.f, 0.f, 0.f};
        float mrun[2] = {-1e30f, -1e30f};
        float lrun[2] = {0.f, 0.f};

        int nt = qt + 1;
        for (int t = 0; t < nt; ++t) {
            int kv0 = t * 128;

            // ---- S^T = K·Q^T, K fragments direct from global ----
            f32x4 st[8][2];
#pragma unroll
            for (int ks = 0; ks < 8; ++ks)
#pragma unroll
                for (int qs = 0; qs < 2; ++qs)
                    st[ks][qs] = (f32x4){-1e30f, -1e30f, -1e30f, -1e30f};
#pragma unroll
            for (int ks = 0; ks < 8; ++ks) {
                if (kv0 + ks * 16 <= qend) {   // wave-uniform causal subtile skip
                    const u16* krow = kkp + (size_t)(kv0 + ks * 16 + lr) * 3072;
                    s16x8 kf0 = *(const s16x8*)(krow + lk * 8);
                    s16x8 kf1 = *(const s16x8*)(krow + 32 + lk * 8);
                    __builtin_amdgcn_s_setprio(1);
#pragma unroll
                    for (int qs = 0; qs < 2; ++qs) {
                        f32x4 z = (f32x4){0.f, 0.f, 0.f, 0.f};
                        z = __builtin_amdgcn_mfma_f32_16x16x32_bf16(kf0, qf[qs][0], z, 0, 0, 0);
                        st[ks][qs] = __builtin_amdgcn_mfma_f32_16x16x32_bf16(kf1, qf[qs][1], z, 0, 0, 0);
                    }
                    __builtin_amdgcn_s_setprio(0);
                }
            }

            if (kv0 + 127 > qbase) {   // diagonal tiles: per-element causal mask
#pragma unroll
                for (int ks = 0; ks < 8; ++ks)
#pragma unroll
                    for (int qs = 0; qs < 2; ++qs)
#pragma unroll
                        for (int r = 0; r < 4; ++r) {
                            int k = kv0 + ks * 16 + lk * 4 + r;
                            int q = qbase + qs * 16 + lr;
                            if (k > q) st[ks][qs][r] = -1e30f;
                        }
            }

            // ---- online softmax (q = lr lane-local; scale folded into exp) ----
#pragma unroll
            for (int qs = 0; qs < 2; ++qs) {
                float pmax = -1e30f;
#pragma unroll
                for (int ks = 0; ks < 8; ++ks) {
                    float a = fmaxf(fmaxf(st[ks][qs][0], st[ks][qs][1]),
                                    fmaxf(st[ks][qs][2], st[ks][qs][3]));
                    pmax = fmaxf(pmax, a);
                }
                pmax = fmaxf(pmax, __shfl_xor(pmax, 16));
                pmax = fmaxf(pmax, __shfl_xor(pmax, 32));
                float mnew = fmaxf(mrun[qs], pmax);
                float scale = __expf((mrun[qs] - mnew) * 0.125f);
                mrun[qs] = mnew;
                float psum = 0.f;
#pragma unroll
                for (int ks = 0; ks < 8; ++ks) {
#pragma unroll
                    for (int r = 0; r < 4; ++r) {
                        float pv = __expf((st[ks][qs][r] - mnew) * 0.125f);
                        st[ks][qs][r] = pv;
                        psum += pv;
                    }
                }
                psum += __shfl_xor(psum, 16);
                psum += __shfl_xor(psum, 32);
                lrun[qs] = lrun[qs] * scale + psum;
#pragma unroll
                for (int ds = 0; ds < 4; ++ds)
#pragma unroll
                    for (int r = 0; r < 4; ++r) acc[qs][ds][r] *= scale;
            }

            // ---- PV via per-wave LDS P, V^T direct from global; two k-halves ----
#pragma unroll
            for (int hh = 0; hh < 2; ++hh) {
                if (kv0 + hh * 64 > qend) break;   // wave-uniform
#pragma unroll
                for (int qs = 0; qs < 2; ++qs)
#pragma unroll
                    for (int ksp = 0; ksp < 4; ++ksp) {
                        int ks = hh * 4 + ksp;
                        uint32_t w0 = cvtpk(st[ks][qs][0], st[ks][qs][1]);
                        uint32_t w1 = cvtpk(st[ks][qs][2], st[ks][qs][3]);
                        int q = qs * 16 + lr;
                        int cp = (2 * ksp + (lk >> 1)) ^ (lr & 7);
                        *(uint2*)&Pl[wid][q * 64 + cp * 8 + (lk & 1) * 4] =
                            make_uint2(w0, w1);
                    }
#pragma unroll
                for (int khp = 0; khp < 2; ++khp) {
                    int kh = hh * 2 + khp;
                    if (kv0 + kh * 32 > qend) break;   // wave-uniform
                    s16x8 vtf[4];
#pragma unroll
                    for (int ds = 0; ds < 4; ++ds)
                        vtf[ds] = *(const s16x8*)(vtp +
                            (size_t)(ds * 16 + lr) * TSEQ + kv0 + kh * 32 + lk * 8);
                    s16x8 pa[2];
#pragma unroll
                    for (int qs = 0; qs < 2; ++qs) {
                        int q = qs * 16 + lr;
                        int cp = (4 * khp + lk) ^ (lr & 7);
                        pa[qs] = *(const s16x8*)&Pl[wid][q * 64 + cp * 8];
                    }
                    __builtin_amdgcn_s_setprio(1);
#pragma unroll
                    for (int qs = 0; qs < 2; ++qs)
#pragma unroll
                        for (int ds = 0; ds < 4; ++ds)
                            acc[qs][ds] = __builtin_amdgcn_mfma_f32_16x16x32_bf16(
                                vtf[ds], pa[qs], acc[qs][ds], 0, 0, 0);
                    __builtin_amdgcn_s_setprio(0);
                }
            }
        }

        // ---- epilogue: acc is O^T (row=d=lk*4+r, col=q=lr) ----
        float rl[2] = {1.f / lrun[0], 1.f / lrun[1]};
#pragma unroll
        for (int qs = 0; qs < 2; ++qs) {
            int q = qbase + qs * 16 + lr;
            u16* yr = y + (size_t)(b * TSEQ + q) * CDIM + h * HDIM;
#pragma unroll
            for (int ds = 0; ds < 4; ++ds)
#pragma unroll
                for (int r = 0; r < 4; ++r)
                    yr[ds * 16 + lk * 4 + r] = f2bu(acc[qs][ds][r] * rl[qs]);
        }
    };

    qtile(pidx);
    qtile(15 - pidx);
}

extern "C" void kernel_launch(void* const* d_in, const int* in_sizes, int n_in,
                              void* d_out, int out_size, void* d_ws, size_t ws_size,
                              hipStream_t stream) {
    (void)in_sizes; (void)n_in; (void)out_size; (void)ws_size;
    const float* x      = (const float*)d_in[0];
    const float* ln1_w  = (const float*)d_in[1];
    const float* w_attn = (const float*)d_in[2];
    const float* w_proj = (const float*)d_in[3];
    const float* ln2_w  = (const float*)d_in[4];
    const float* w_fc1  = (const float*)d_in[5];
    const float* b_fc1  = (const float*)d_in[6];
    const float* w_fc2  = (const float*)d_in[7];
    const float* b_fc2  = (const float*)d_in[8];
    float* out = (float*)d_out;
    char* ws = (char*)d_ws;

    u16*   wT_attn = (u16*)(ws + 0);            // [3072][1024] bf16, 6 MB
    u16*   wT_proj = (u16*)(ws + 6291456);      // [1024][1024], 2 MB
    u16*   wT_fc1  = (u16*)(ws + 8388608);      // [4096][1024], 8 MB
    u16*   wT_fc2  = (u16*)(ws + 16777216);     // [1024][4096], 8 MB
    u16*   h       = (u16*)(ws + 25165824);     // [8192][1024]
    u16*   qkvb    = (u16*)(ws + 41943040);     // [8192][3072]
    u16*   yb      = (u16*)(ws + 92274688);     // [8192][1024]
    float* x1      = (float*)(ws + 109051904);  // [8192][1024] f32
    u16*   vTb     = (u16*)(ws + 109051904);    // [64][64][2048] bf16 (aliases x1;
                                                // vT dead before proj writes x1)
    u16*   h3      = (u16*)(ws + 41943040);     // [8192][4096] reuses qkv region

    twb_k<<<dim3(3072 / 32, 1024 / 32), 256, 0, stream>>>(w_attn, wT_attn, 1024, 3072);
    twb_k<<<dim3(1024 / 32, 1024 / 32), 256, 0, stream>>>(w_proj, wT_proj, 1024, 1024);
    twb_k<<<dim3(4096 / 32, 1024 / 32), 256, 0, stream>>>(w_fc1, wT_fc1, 1024, 4096);
    twb_k<<<dim3(1024 / 32, 4096 / 32), 256, 0, stream>>>(w_fc2, wT_fc2, 4096, 1024);

    ln_k<<<8192, 256, 0, stream>>>(x, ln1_w, h);
    gemm8p<0><<<dim3(3072 / 256, 8192 / 256), 512, 0, stream>>>(h, wT_attn, qkvb, vTb, nullptr, 8192, 3072, 1024);
    attn_k<<<dim3(8, NBATCH * NHEAD), 256, 0, stream>>>(qkvb, vTb, yb);
    gemm_bt<1><<<dim3(1024 / 128, 8192 / 128), 256, 0, stream>>>(yb, wT_proj, x1, nullptr, x, 8192, 1024, 1024);
    ln_k<<<8192, 256, 0, stream>>>(x1, ln2_w, h);
    gemm8p<2><<<dim3(4096 / 256, 8192 / 256), 512, 0, stream>>>(h, wT_fc1, h3, nullptr, b_fc1, 8192, 4096, 1024);
    gemm_bt<3><<<dim3(1024 / 128, 8192 / 128), 256, 0, stream>>>(h3, wT_fc2, out, b_fc2, x1, 8192, 1024, 4096);
}